// Round 4
// baseline (635.358 us; speedup 1.0000x reference)
//
#include <hip/hip_runtime.h>
#include <stdint.h>

#define S_TOK 16384
#define M_DIM 512
#define E_EXP 16
#define D_OUT 256
#define H1D 500
#define H2D 500
#define H3D 1000

typedef float f32x4 __attribute__((ext_vector_type(4)));
typedef short s16x8 __attribute__((ext_vector_type(8)));

__device__ __forceinline__ unsigned short f2bf(float f) {
  unsigned int u = __float_as_uint(f);
  u += 0x7fffu + ((u >> 16) & 1u);
  return (unsigned short)(u >> 16);
}

// async global->LDS, 16B per lane; LDS dest = wave-uniform base + lane*16
__device__ __forceinline__ void ld_lds16(const unsigned short* g, unsigned short* l) {
  __builtin_amdgcn_global_load_lds(
      (const __attribute__((address_space(1))) unsigned int*)(const void*)g,
      (__attribute__((address_space(3))) unsigned int*)(void*)l, 16, 0, 0);
}

struct TokenRec { int i1, i2; float g1, g2; };

// ---------------- init: zero final_output + cursor ----------------
__global__ __launch_bounds__(256) void k_init(float* __restrict__ out0,
                                              unsigned int* __restrict__ cursor) {
  int idx = blockIdx.x * 256 + threadIdx.x;        // grid covers S*D/4 exactly
  f32x4 z = {0.f, 0.f, 0.f, 0.f};
  *(f32x4*)&out0[(size_t)idx * 4] = z;
  if (blockIdx.x == 0 && threadIdx.x < E_EXP) cursor[threadIdx.x] = 0u;
}

// ---------------- router: lane-parallel experts, f64 accum, no global atomics ------
__global__ __launch_bounds__(256) void k_router(const float* __restrict__ x,
                                                const float* __restrict__ noise,
                                                const float* __restrict__ Wr,
                                                float* __restrict__ sel_out,
                                                float* __restrict__ sel_buf,
                                                TokenRec* __restrict__ te) {
  __shared__ float wr[E_EXP * 516];   // pad 516: 2-way LDS aliasing only (free)
  int t = threadIdx.x;
  for (int i = t; i < E_EXP * M_DIM; i += 256) {
    int e = i >> 9, m = i & 511;
    wr[e * 516 + m] = Wr[i];
  }
  __syncthreads();

  int wv = t >> 6, l = t & 63;
  int e = l & 15, tg = l >> 4;                  // expert, token-slot in wave
  int s = blockIdx.x * 16 + wv * 4 + tg;        // token id

  const float* xr = x + (size_t)s * M_DIM;
  const float* wre = &wr[e * 516];
  double a0 = 0.0, a1 = 0.0, a2 = 0.0, a3 = 0.0;
#pragma unroll 4
  for (int m = 0; m < M_DIM; m += 4) {
    f32x4 xv = *(const f32x4*)(xr + m);
    f32x4 wv4 = *(const f32x4*)(wre + m);
    a0 += (double)xv.x * (double)wv4.x;
    a1 += (double)xv.y * (double)wv4.y;
    a2 += (double)xv.z * (double)wv4.z;
    a3 += (double)xv.w * (double)wv4.w;
  }
  double a = (a0 + a1) + (a2 + a3);
  a += (double)noise[(size_t)s * E_EXP + e];

  double mx = a;
#pragma unroll
  for (int off = 8; off >= 1; off >>= 1) { double o = __shfl_xor(mx, off, 64); mx = (o > mx) ? o : mx; }
  double p = exp(a - mx);
  double sum = p;
#pragma unroll
  for (int off = 8; off >= 1; off >>= 1) sum += __shfl_xor(sum, off, 64);
  sel_buf[(size_t)s * E_EXP + e] = (float)(p / sum);

  unsigned long long pb = __double_as_longlong(p);
  unsigned long long key = (pb & ~0xFFull) | (unsigned long long)(255 - e);
  unsigned long long k1 = key;
#pragma unroll
  for (int off = 8; off >= 1; off >>= 1) { unsigned long long o = __shfl_xor(k1, off, 64); k1 = (o > k1) ? o : k1; }
  int i1 = 255 - (int)(k1 & 0xFFull);
  unsigned long long key2 = (e == i1) ? 0ull : key;
  unsigned long long k2 = key2;
#pragma unroll
  for (int off = 8; off >= 1; off >>= 1) { unsigned long long o = __shfl_xor(k2, off, 64); k2 = (o > k2) ? o : k2; }
  int i2 = 255 - (int)(k2 & 0xFFull);

  double p1 = __shfl(p, tg * 16 + i1, 64);
  double p2 = __shfl(p, tg * 16 + i2, 64);

  sel_out[(size_t)s * E_EXP + e] = (e == i1 || e == i2) ? 1.f : 0.f;
  if (e == 0) {
    double inv = 1.0 / (p1 + p2);
    TokenRec r; r.i1 = i1; r.i2 = i2; r.g1 = (float)(p1 * inv); r.g2 = (float)(p2 * inv);
    te[s] = r;
  }
}

// ---------------- stats: per-block proxy partial sums + histogram ----------------
__global__ __launch_bounds__(256) void k_stats(const float* __restrict__ sel_buf,
                                               const TokenRec* __restrict__ te,
                                               float* __restrict__ partials) {  // [16][32]
  __shared__ float psum[256];
  __shared__ unsigned int hist[E_EXP];
  int t = threadIdx.x, b = blockIdx.x;
  if (t < E_EXP) hist[t] = 0u;
  __syncthreads();
  int e = t & 15, rg = t >> 4;
  int base = b * 1024;
  float acc = 0.f;
#pragma unroll 4
  for (int i = 0; i < 64; i++)
    acc += sel_buf[(size_t)(base + i * 16 + rg) * E_EXP + e];
  for (int i = t; i < 1024; i += 256) {
    TokenRec r = te[base + i];
    atomicAdd(&hist[r.i1], 1u);   // LDS atomics
    atomicAdd(&hist[r.i2], 1u);
  }
  psum[t] = acc;
  __syncthreads();
  if (t < E_EXP) {
    float v = 0.f;
#pragma unroll
    for (int rg2 = 0; rg2 < 16; rg2++) v += psum[rg2 * 16 + t];
    partials[b * 32 + t] = v;
    partials[b * 32 + 16 + t] = (float)hist[t];
  }
}

// ---------------- reduce partials -> counts/offsets + balance loss ----------------
__global__ void k_prefix_loss(const float* __restrict__ partials,
                              unsigned int* __restrict__ counts,
                              unsigned int* __restrict__ offsets,
                              float* __restrict__ out_loss) {
  __shared__ float pr[E_EXP];
  __shared__ unsigned int cn[E_EXP];
  int t = threadIdx.x;
  if (t < E_EXP) {
    float p = 0.f, c = 0.f;
    for (int b = 0; b < 16; b++) { p += partials[b * 32 + t]; c += partials[b * 32 + 16 + t]; }
    pr[t] = p; cn[t] = (unsigned int)(c + 0.5f);
  }
  __syncthreads();
  if (t == 0) {
    unsigned int acc = 0; float ls = 0.f;
    for (int e = 0; e < E_EXP; e++) {
      counts[e] = cn[e];
      offsets[e] = acc;
      acc += cn[e];
      ls += pr[e] * (float)cn[e];
    }
    out_loss[0] = ls * ((float)E_EXP / ((float)S_TOK * (float)S_TOK));
    out_loss[1] = 0.f;
  }
}

// ---------------- listbuild: block-level reservation ----------------
__global__ __launch_bounds__(256) void k_listbuild(const TokenRec* __restrict__ te,
                                                   const unsigned int* __restrict__ offsets,
                                                   unsigned int* __restrict__ cursor,
                                                   int* __restrict__ slot_token,
                                                   float* __restrict__ slot_gate) {
  __shared__ unsigned int lhist[E_EXP];
  __shared__ unsigned int lbase[E_EXP];
  __shared__ unsigned int lcur[E_EXP];
  int t = threadIdx.x, b = blockIdx.x;
  int base = b * 1024;
  if (t < E_EXP) lhist[t] = 0u;
  __syncthreads();
  for (int i = t; i < 1024; i += 256) {
    TokenRec r = te[base + i];
    atomicAdd(&lhist[r.i1], 1u);
    atomicAdd(&lhist[r.i2], 1u);
  }
  __syncthreads();
  if (t < E_EXP) {
    lbase[t] = offsets[t] + atomicAdd(&cursor[t], lhist[t]);
    lcur[t] = 0u;
  }
  __syncthreads();
  for (int i = t; i < 1024; i += 256) {
    int s = base + i;
    TokenRec r = te[s];
    unsigned int p1 = atomicAdd(&lcur[r.i1], 1u);
    int sl1 = (int)(lbase[r.i1] + p1);
    slot_token[sl1] = s; slot_gate[sl1] = r.g1;
    unsigned int p2 = atomicAdd(&lcur[r.i2], 1u);
    int sl2 = (int)(lbase[r.i2] + p2);
    slot_token[sl2] = s; slot_gate[sl2] = r.g2;
  }
}

// ---------------- gather x rows -> bf16 compact activations ----------------
__global__ __launch_bounds__(256) void k_gather(const float* __restrict__ x,
                                                const int* __restrict__ slot_token,
                                                unsigned short* __restrict__ xg) {
  int idx = blockIdx.x * 256 + threadIdx.x;  // 32768*128 total
  int row = idx >> 7, q = idx & 127;
  int tkn = slot_token[row];
  f32x4 v = *(const f32x4*)&x[(size_t)tkn * M_DIM + q * 4];
  ushort4 o;
  o.x = f2bf(v.x); o.y = f2bf(v.y); o.z = f2bf(v.z); o.w = f2bf(v.w);
  *(ushort4*)&xg[(size_t)row * 512 + q * 4] = o;
}

// ---------------- weight convert: f32 [E][Kr][Nr] -> bf16 transposed padded [E][Np][Kp]
__global__ __launch_bounds__(256) void k_convw(const float* __restrict__ src,
                                               unsigned short* __restrict__ dst,
                                               int Kr, int Nr, int Kp, int Np) {
  __shared__ float tile[64][65];
  int e = blockIdx.z;
  int k0 = blockIdx.x * 64, n0 = blockIdx.y * 64;
  int t = threadIdx.x;
  int cx = t & 63, ry = t >> 6;  // ry 0..3
  const float* sp = src + (size_t)e * Kr * Nr;
#pragma unroll
  for (int i = 0; i < 16; i++) {
    int k = k0 + ry + i * 4, n = n0 + cx;
    float v = (k < Kr && n < Nr) ? sp[(size_t)k * Nr + n] : 0.f;
    tile[ry + i * 4][cx] = v;
  }
  __syncthreads();
  unsigned short* dp = dst + (size_t)e * Np * Kp;
#pragma unroll
  for (int i = 0; i < 16; i++) {
    int nl = ry + i * 4, kl = cx;
    dp[(size_t)(n0 + nl) * Kp + k0 + kl] = f2bf(tile[kl][nl]);
  }
}

// ---------------- grouped GEMM v3: 128x128 tile, BK=32, double-buffered LDS,
// ONE barrier per K-step (loads for k+1 issued post-barrier, latency hidden by compute)
// mid: out = relu(in @ W^T + b) -> bf16 (pad cols zeroed)
__global__ __launch_bounds__(256) void k_gemm_mid(const unsigned short* __restrict__ in,
                                                  const unsigned short* __restrict__ wt,
                                                  const float* __restrict__ bias,
                                                  unsigned short* __restrict__ out,
                                                  const unsigned int* __restrict__ offsets,
                                                  const unsigned int* __restrict__ counts,
                                                  int KP, int NP, int NREAL) {
  int e = blockIdx.z;
  int n_e = (int)counts[e];
  if (n_e == 0) return;
  int base = (int)offsets[e];
  int bn = blockIdx.y;
  __shared__ unsigned short As[2][128 * 32];   // 2 x 8 KB
  __shared__ unsigned short Bs[2][128 * 32];
  int t = threadIdx.x;
  int w = t >> 6, l = t & 63;
  int wm = w & 1, wn = w >> 1;
  int lr = l & 15, lq = l >> 4;
  int c0 = w * 2, c1 = w * 2 + 1;          // this wave's two 16-row chunks
  int lrow = l >> 2, lseg = l & 3;         // staging: row-in-chunk, 16B segment

  const unsigned short* bW = wt + (size_t)e * NP * KP;
  const unsigned short* bp0 = bW + (size_t)(bn * 128 + c0 * 16 + lrow) * KP + lseg * 8;
  const unsigned short* bp1 = bW + (size_t)(bn * 128 + c1 * 16 + lrow) * KP + lseg * 8;
  unsigned short* lA0[2] = {&As[0][c0 * 512], &As[1][c0 * 512]};
  unsigned short* lA1[2] = {&As[0][c1 * 512], &As[1][c1 * 512]};
  unsigned short* lB0[2] = {&Bs[0][c0 * 512], &Bs[1][c0 * 512]};
  unsigned short* lB1[2] = {&Bs[0][c1 * 512], &Bs[1][c1 * 512]};
  int aoff = (wm * 64 + lr) * 32 + lq * 8;
  int boff = (wn * 64 + lr) * 32 + lq * 8;
  int nk = KP >> 5;

  for (int bm = blockIdx.x; bm * 128 < n_e; bm += gridDim.x) {
    int r0 = bm * 128 + c0 * 16 + lrow; r0 = (r0 < n_e) ? r0 : (n_e - 1);
    int r1 = bm * 128 + c1 * 16 + lrow; r1 = (r1 < n_e) ? r1 : (n_e - 1);
    const unsigned short* ap0 = in + (size_t)(base + r0) * KP + lseg * 8;
    const unsigned short* ap1 = in + (size_t)(base + r1) * KP + lseg * 8;
    const unsigned short* bq0 = bp0;
    const unsigned short* bq1 = bp1;
    f32x4 acc[4][4];
#pragma unroll
    for (int i = 0; i < 4; i++)
#pragma unroll
      for (int j = 0; j < 4; j++) acc[i][j] = (f32x4){0.f, 0.f, 0.f, 0.f};

    // prologue: stage k-step 0 into buffer 0
    ld_lds16(ap0, lA0[0]); ld_lds16(ap1, lA1[0]);
    ld_lds16(bq0, lB0[0]); ld_lds16(bq1, lB1[0]);
    ap0 += 32; ap1 += 32; bq0 += 32; bq1 += 32;

    for (int ks = 0; ks < nk; ks++) {
      int cb = ks & 1, nb = cb ^ 1;
      __syncthreads();   // drains vmcnt: buf[cb] ready; all waves done reading buf[nb]
      if (ks + 1 < nk) {
        ld_lds16(ap0, lA0[nb]); ld_lds16(ap1, lA1[nb]);
        ld_lds16(bq0, lB0[nb]); ld_lds16(bq1, lB1[nb]);
        ap0 += 32; ap1 += 32; bq0 += 32; bq1 += 32;
      }
      s16x8 af[4], bf[4];
#pragma unroll
      for (int mt = 0; mt < 4; mt++) af[mt] = *(const s16x8*)&As[cb][aoff + mt * 512];
#pragma unroll
      for (int nt = 0; nt < 4; nt++) bf[nt] = *(const s16x8*)&Bs[cb][boff + nt * 512];
#pragma unroll
      for (int mt = 0; mt < 4; mt++)
#pragma unroll
        for (int nt = 0; nt < 4; nt++)
          acc[mt][nt] = __builtin_amdgcn_mfma_f32_16x16x32_bf16(af[mt], bf[nt], acc[mt][nt], 0, 0, 0);
    }

#pragma unroll
    for (int nt = 0; nt < 4; nt++) {
      int col = bn * 128 + wn * 64 + nt * 16 + lr;
      bool cok = col < NREAL;
      float bv = cok ? bias[(size_t)e * NREAL + col] : 0.f;
#pragma unroll
      for (int mt = 0; mt < 4; mt++)
#pragma unroll
        for (int reg = 0; reg < 4; reg++) {
          int r = bm * 128 + wm * 64 + mt * 16 + lq * 4 + reg;
          if (r < n_e) {
            float v = cok ? fmaxf(acc[mt][nt][reg] + bv, 0.f) : 0.f;
            out[(size_t)(base + r) * NP + col] = f2bf(v);
          }
        }
    }
  }
}

// fin: scatter gate*(h3@W4+b4) into final output via f32 atomics (2 addends/elem)
__global__ __launch_bounds__(256) void k_gemm_fin(const unsigned short* __restrict__ in,
                                                  const unsigned short* __restrict__ wt,
                                                  const float* __restrict__ bias,
                                                  float* __restrict__ dout,
                                                  const unsigned int* __restrict__ offsets,
                                                  const unsigned int* __restrict__ counts,
                                                  const int* __restrict__ slot_token,
                                                  const float* __restrict__ slot_gate) {
  const int KP = 1024, NP = 256;
  int e = blockIdx.z;
  int n_e = (int)counts[e];
  if (n_e == 0) return;
  int base = (int)offsets[e];
  int bn = blockIdx.y;
  __shared__ unsigned short As[2][128 * 32];
  __shared__ unsigned short Bs[2][128 * 32];
  int t = threadIdx.x;
  int w = t >> 6, l = t & 63;
  int wm = w & 1, wn = w >> 1;
  int lr = l & 15, lq = l >> 4;
  int c0 = w * 2, c1 = w * 2 + 1;
  int lrow = l >> 2, lseg = l & 3;

  const unsigned short* bW = wt + (size_t)e * NP * KP;
  const unsigned short* bp0 = bW + (size_t)(bn * 128 + c0 * 16 + lrow) * KP + lseg * 8;
  const unsigned short* bp1 = bW + (size_t)(bn * 128 + c1 * 16 + lrow) * KP + lseg * 8;
  unsigned short* lA0[2] = {&As[0][c0 * 512], &As[1][c0 * 512]};
  unsigned short* lA1[2] = {&As[0][c1 * 512], &As[1][c1 * 512]};
  unsigned short* lB0[2] = {&Bs[0][c0 * 512], &Bs[1][c0 * 512]};
  unsigned short* lB1[2] = {&Bs[0][c1 * 512], &Bs[1][c1 * 512]};
  int aoff = (wm * 64 + lr) * 32 + lq * 8;
  int boff = (wn * 64 + lr) * 32 + lq * 8;
  int nk = KP >> 5;

  for (int bm = blockIdx.x; bm * 128 < n_e; bm += gridDim.x) {
    int r0 = bm * 128 + c0 * 16 + lrow; r0 = (r0 < n_e) ? r0 : (n_e - 1);
    int r1 = bm * 128 + c1 * 16 + lrow; r1 = (r1 < n_e) ? r1 : (n_e - 1);
    const unsigned short* ap0 = in + (size_t)(base + r0) * KP + lseg * 8;
    const unsigned short* ap1 = in + (size_t)(base + r1) * KP + lseg * 8;
    const unsigned short* bq0 = bp0;
    const unsigned short* bq1 = bp1;
    f32x4 acc[4][4];
#pragma unroll
    for (int i = 0; i < 4; i++)
#pragma unroll
      for (int j = 0; j < 4; j++) acc[i][j] = (f32x4){0.f, 0.f, 0.f, 0.f};

    ld_lds16(ap0, lA0[0]); ld_lds16(ap1, lA1[0]);
    ld_lds16(bq0, lB0[0]); ld_lds16(bq1, lB1[0]);
    ap0 += 32; ap1 += 32; bq0 += 32; bq1 += 32;

    for (int ks = 0; ks < nk; ks++) {
      int cb = ks & 1, nb = cb ^ 1;
      __syncthreads();
      if (ks + 1 < nk) {
        ld_lds16(ap0, lA0[nb]); ld_lds16(ap1, lA1[nb]);
        ld_lds16(bq0, lB0[nb]); ld_lds16(bq1, lB1[nb]);
        ap0 += 32; ap1 += 32; bq0 += 32; bq1 += 32;
      }
      s16x8 af[4], bf[4];
#pragma unroll
      for (int mt = 0; mt < 4; mt++) af[mt] = *(const s16x8*)&As[cb][aoff + mt * 512];
#pragma unroll
      for (int nt = 0; nt < 4; nt++) bf[nt] = *(const s16x8*)&Bs[cb][boff + nt * 512];
#pragma unroll
      for (int mt = 0; mt < 4; mt++)
#pragma unroll
        for (int nt = 0; nt < 4; nt++)
          acc[mt][nt] = __builtin_amdgcn_mfma_f32_16x16x32_bf16(af[mt], bf[nt], acc[mt][nt], 0, 0, 0);
    }

#pragma unroll
    for (int mt = 0; mt < 4; mt++)
#pragma unroll
      for (int reg = 0; reg < 4; reg++) {
        int r = bm * 128 + wm * 64 + mt * 16 + lq * 4 + reg;
        if (r < n_e) {
          int gr = base + r;
          int tk = slot_token[gr];
          float g = slot_gate[gr];
#pragma unroll
          for (int nt = 0; nt < 4; nt++) {
            int col = bn * 128 + wn * 64 + nt * 16 + lr;
            float v = acc[mt][nt][reg] + bias[(size_t)e * 256 + col];
            atomicAdd(&dout[(size_t)tk * D_OUT + col], g * v);
          }
        }
      }
  }
}

extern "C" void kernel_launch(void* const* d_in, const int* in_sizes, int n_in,
                              void* d_out, int out_size, void* d_ws, size_t ws_size,
                              hipStream_t stream) {
  const float* x    = (const float*)d_in[0];
  const float* nois = (const float*)d_in[1];
  const float* Wr   = (const float*)d_in[2];
  const float* W1   = (const float*)d_in[3];
  const float* b1   = (const float*)d_in[4];
  const float* W2   = (const float*)d_in[5];
  const float* b2   = (const float*)d_in[6];
  const float* W3   = (const float*)d_in[7];
  const float* b3   = (const float*)d_in[8];
  const float* W4   = (const float*)d_in[9];
  const float* b4   = (const float*)d_in[10];
  float* out = (float*)d_out;

  char* w = (char*)d_ws;
  unsigned short* actA = (unsigned short*)(w + 0);             // 32768*1024 bf16 = 67108864 B
  unsigned short* actB = (unsigned short*)(w + 67108864);      // 32768*512 bf16  = 33554432 B
  unsigned short* Wt   = (unsigned short*)(w + 100663296);     // <=16*512*1024 bf16 = 16777216 B
  int*            slot_token = (int*)(w + 117440512);          // 131072 B
  float*          slot_gate  = (float*)(w + 117571584);        // 131072 B
  TokenRec*       te         = (TokenRec*)(w + 117702656);     // 262144 B
  unsigned int*   counts  = (unsigned int*)(w + 117964800);
  unsigned int*   cursor  = (unsigned int*)(w + 117964864);
  unsigned int*   offsets = (unsigned int*)(w + 117964928);
  // transient (dead before GEMM L1 writes actA): overlay on actA region
  float*          sel_buf  = (float*)(w + 0);                  // 16384*16 f32 = 1 MB
  float*          partials = (float*)(w + 1048576);            // 16*32 f32 = 2 KB

  float* sel_out  = out + (size_t)S_TOK * D_OUT;
  float* loss_out = out + (size_t)S_TOK * D_OUT + (size_t)S_TOK * E_EXP;

  k_init<<<dim3((S_TOK * D_OUT) / 1024), dim3(256), 0, stream>>>(out, cursor);
  k_router<<<dim3(S_TOK / 16), dim3(256), 0, stream>>>(x, nois, Wr, sel_out, sel_buf, te);
  k_stats<<<dim3(16), dim3(256), 0, stream>>>(sel_buf, te, partials);
  k_prefix_loss<<<dim3(1), dim3(64), 0, stream>>>(partials, counts, offsets, loss_out);
  k_listbuild<<<dim3(16), dim3(256), 0, stream>>>(te, offsets, cursor, slot_token, slot_gate);
  k_gather<<<dim3((2 * S_TOK * 128) / 256), dim3(256), 0, stream>>>(x, slot_token, actB);

  // Layer 1: [*,512] @ [512,500] -> relu -> actA (stride 512)
  k_convw<<<dim3(8, 8, E_EXP), dim3(256), 0, stream>>>(W1, Wt, 512, H1D, 512, 512);
  k_gemm_mid<<<dim3(32, 4, E_EXP), dim3(256), 0, stream>>>(actB, Wt, b1, actA, offsets, counts, 512, 512, H1D);
  // Layer 2: [*,500] @ [500,500] -> relu -> actB (stride 512)
  k_convw<<<dim3(8, 8, E_EXP), dim3(256), 0, stream>>>(W2, Wt, H1D, H2D, 512, 512);
  k_gemm_mid<<<dim3(32, 4, E_EXP), dim3(256), 0, stream>>>(actA, Wt, b2, actB, offsets, counts, 512, 512, H2D);
  // Layer 3: [*,500] @ [500,1000] -> relu -> actA (stride 1024)
  k_convw<<<dim3(8, 16, E_EXP), dim3(256), 0, stream>>>(W3, Wt, H2D, H3D, 512, 1024);
  k_gemm_mid<<<dim3(32, 8, E_EXP), dim3(256), 0, stream>>>(actB, Wt, b3, actA, offsets, counts, 512, 1024, H3D);
  // Layer 4: [*,1000] @ [1000,256] -> scatter gate-weighted into out
  k_convw<<<dim3(16, 4, E_EXP), dim3(256), 0, stream>>>(W4, Wt, H3D, D_OUT, 1024, 256);
  k_gemm_fin<<<dim3(32, 2, E_EXP), dim3(256), 0, stream>>>(actA, Wt, b4, out, offsets, counts, slot_token, slot_gate);

  (void)in_sizes; (void)n_in; (void)out_size; (void)ws_size;
}

// Round 5
// 506.991 us; speedup vs baseline: 1.2532x; 1.2532x over previous
//
#include <hip/hip_runtime.h>
#include <stdint.h>

#define S_TOK 16384
#define M_DIM 512
#define E_EXP 16
#define D_OUT 256
#define H1D 500
#define H2D 500
#define H3D 1000

typedef float f32x4 __attribute__((ext_vector_type(4)));
typedef short s16x8 __attribute__((ext_vector_type(8)));

__device__ __forceinline__ unsigned short f2bf(float f) {
  unsigned int u = __float_as_uint(f);
  u += 0x7fffu + ((u >> 16) & 1u);
  return (unsigned short)(u >> 16);
}

// async global->LDS, 16B per lane; LDS dest = wave-uniform base + lane*16
__device__ __forceinline__ void ld_lds16(const unsigned short* g, unsigned short* l) {
  __builtin_amdgcn_global_load_lds(
      (const __attribute__((address_space(1))) unsigned int*)(const void*)g,
      (__attribute__((address_space(3))) unsigned int*)(void*)l, 16, 0, 0);
}

struct TokenRec { int i1, i2; float g1, g2; };

// ---------------- init: zero final_output + cursor ----------------
__global__ __launch_bounds__(256) void k_init(float* __restrict__ out0,
                                              unsigned int* __restrict__ cursor) {
  int idx = blockIdx.x * 256 + threadIdx.x;        // grid covers S*D/4 exactly
  f32x4 z = {0.f, 0.f, 0.f, 0.f};
  *(f32x4*)&out0[(size_t)idx * 4] = z;
  if (blockIdx.x == 0 && threadIdx.x < E_EXP) cursor[threadIdx.x] = 0u;
}

// ---------------- router: lane-parallel experts, f64 accum, no global atomics ------
__global__ __launch_bounds__(256) void k_router(const float* __restrict__ x,
                                                const float* __restrict__ noise,
                                                const float* __restrict__ Wr,
                                                float* __restrict__ sel_out,
                                                float* __restrict__ sel_buf,
                                                TokenRec* __restrict__ te) {
  __shared__ float wr[E_EXP * 516];   // pad 516: 2-way LDS aliasing only (free)
  int t = threadIdx.x;
  for (int i = t; i < E_EXP * M_DIM; i += 256) {
    int e = i >> 9, m = i & 511;
    wr[e * 516 + m] = Wr[i];
  }
  __syncthreads();

  int wv = t >> 6, l = t & 63;
  int e = l & 15, tg = l >> 4;                  // expert, token-slot in wave
  int s = blockIdx.x * 16 + wv * 4 + tg;        // token id

  const float* xr = x + (size_t)s * M_DIM;
  const float* wre = &wr[e * 516];
  double a0 = 0.0, a1 = 0.0, a2 = 0.0, a3 = 0.0;
#pragma unroll 4
  for (int m = 0; m < M_DIM; m += 4) {
    f32x4 xv = *(const f32x4*)(xr + m);
    f32x4 wv4 = *(const f32x4*)(wre + m);
    a0 += (double)xv.x * (double)wv4.x;
    a1 += (double)xv.y * (double)wv4.y;
    a2 += (double)xv.z * (double)wv4.z;
    a3 += (double)xv.w * (double)wv4.w;
  }
  double a = (a0 + a1) + (a2 + a3);
  a += (double)noise[(size_t)s * E_EXP + e];

  double mx = a;
#pragma unroll
  for (int off = 8; off >= 1; off >>= 1) { double o = __shfl_xor(mx, off, 64); mx = (o > mx) ? o : mx; }
  double p = exp(a - mx);
  double sum = p;
#pragma unroll
  for (int off = 8; off >= 1; off >>= 1) sum += __shfl_xor(sum, off, 64);
  sel_buf[(size_t)s * E_EXP + e] = (float)(p / sum);

  unsigned long long pb = __double_as_longlong(p);
  unsigned long long key = (pb & ~0xFFull) | (unsigned long long)(255 - e);
  unsigned long long k1 = key;
#pragma unroll
  for (int off = 8; off >= 1; off >>= 1) { unsigned long long o = __shfl_xor(k1, off, 64); k1 = (o > k1) ? o : k1; }
  int i1 = 255 - (int)(k1 & 0xFFull);
  unsigned long long key2 = (e == i1) ? 0ull : key;
  unsigned long long k2 = key2;
#pragma unroll
  for (int off = 8; off >= 1; off >>= 1) { unsigned long long o = __shfl_xor(k2, off, 64); k2 = (o > k2) ? o : k2; }
  int i2 = 255 - (int)(k2 & 0xFFull);

  double p1 = __shfl(p, tg * 16 + i1, 64);
  double p2 = __shfl(p, tg * 16 + i2, 64);

  sel_out[(size_t)s * E_EXP + e] = (e == i1 || e == i2) ? 1.f : 0.f;
  if (e == 0) {
    double inv = 1.0 / (p1 + p2);
    TokenRec r; r.i1 = i1; r.i2 = i2; r.g1 = (float)(p1 * inv); r.g2 = (float)(p2 * inv);
    te[s] = r;
  }
}

// ---------------- stats: per-block proxy partial sums + histogram ----------------
__global__ __launch_bounds__(256) void k_stats(const float* __restrict__ sel_buf,
                                               const TokenRec* __restrict__ te,
                                               float* __restrict__ partials) {  // [16][32]
  __shared__ float psum[256];
  __shared__ unsigned int hist[E_EXP];
  int t = threadIdx.x, b = blockIdx.x;
  if (t < E_EXP) hist[t] = 0u;
  __syncthreads();
  int e = t & 15, rg = t >> 4;
  int base = b * 1024;
  float acc = 0.f;
#pragma unroll 4
  for (int i = 0; i < 64; i++)
    acc += sel_buf[(size_t)(base + i * 16 + rg) * E_EXP + e];
  for (int i = t; i < 1024; i += 256) {
    TokenRec r = te[base + i];
    atomicAdd(&hist[r.i1], 1u);   // LDS atomics
    atomicAdd(&hist[r.i2], 1u);
  }
  psum[t] = acc;
  __syncthreads();
  if (t < E_EXP) {
    float v = 0.f;
#pragma unroll
    for (int rg2 = 0; rg2 < 16; rg2++) v += psum[rg2 * 16 + t];
    partials[b * 32 + t] = v;
    partials[b * 32 + 16 + t] = (float)hist[t];
  }
}

// ---------------- reduce partials -> counts/offsets + balance loss ----------------
__global__ void k_prefix_loss(const float* __restrict__ partials,
                              unsigned int* __restrict__ counts,
                              unsigned int* __restrict__ offsets,
                              float* __restrict__ out_loss) {
  __shared__ float pr[E_EXP];
  __shared__ unsigned int cn[E_EXP];
  int t = threadIdx.x;
  if (t < E_EXP) {
    float p = 0.f, c = 0.f;
    for (int b = 0; b < 16; b++) { p += partials[b * 32 + t]; c += partials[b * 32 + 16 + t]; }
    pr[t] = p; cn[t] = (unsigned int)(c + 0.5f);
  }
  __syncthreads();
  if (t == 0) {
    unsigned int acc = 0; float ls = 0.f;
    for (int e = 0; e < E_EXP; e++) {
      counts[e] = cn[e];
      offsets[e] = acc;
      acc += cn[e];
      ls += pr[e] * (float)cn[e];
    }
    out_loss[0] = ls * ((float)E_EXP / ((float)S_TOK * (float)S_TOK));
    out_loss[1] = 0.f;
  }
}

// ---------------- listbuild: block-level reservation ----------------
__global__ __launch_bounds__(256) void k_listbuild(const TokenRec* __restrict__ te,
                                                   const unsigned int* __restrict__ offsets,
                                                   unsigned int* __restrict__ cursor,
                                                   int* __restrict__ slot_token,
                                                   float* __restrict__ slot_gate) {
  __shared__ unsigned int lhist[E_EXP];
  __shared__ unsigned int lbase[E_EXP];
  __shared__ unsigned int lcur[E_EXP];
  int t = threadIdx.x, b = blockIdx.x;
  int base = b * 1024;
  if (t < E_EXP) lhist[t] = 0u;
  __syncthreads();
  for (int i = t; i < 1024; i += 256) {
    TokenRec r = te[base + i];
    atomicAdd(&lhist[r.i1], 1u);
    atomicAdd(&lhist[r.i2], 1u);
  }
  __syncthreads();
  if (t < E_EXP) {
    lbase[t] = offsets[t] + atomicAdd(&cursor[t], lhist[t]);
    lcur[t] = 0u;
  }
  __syncthreads();
  for (int i = t; i < 1024; i += 256) {
    int s = base + i;
    TokenRec r = te[s];
    unsigned int p1 = atomicAdd(&lcur[r.i1], 1u);
    int sl1 = (int)(lbase[r.i1] + p1);
    slot_token[sl1] = s; slot_gate[sl1] = r.g1;
    unsigned int p2 = atomicAdd(&lcur[r.i2], 1u);
    int sl2 = (int)(lbase[r.i2] + p2);
    slot_token[sl2] = s; slot_gate[sl2] = r.g2;
  }
}

// ---------------- gather x rows -> bf16 compact activations ----------------
__global__ __launch_bounds__(256) void k_gather(const float* __restrict__ x,
                                                const int* __restrict__ slot_token,
                                                unsigned short* __restrict__ xg) {
  int idx = blockIdx.x * 256 + threadIdx.x;  // 32768*128 total
  int row = idx >> 7, q = idx & 127;
  int tkn = slot_token[row];
  f32x4 v = *(const f32x4*)&x[(size_t)tkn * M_DIM + q * 4];
  ushort4 o;
  o.x = f2bf(v.x); o.y = f2bf(v.y); o.z = f2bf(v.z); o.w = f2bf(v.w);
  *(ushort4*)&xg[(size_t)row * 512 + q * 4] = o;
}

// ---------------- weight convert: f32 [E][Kr][Nr] -> bf16 transposed padded [E][Np][Kp]
__global__ __launch_bounds__(256) void k_convw(const float* __restrict__ src,
                                               unsigned short* __restrict__ dst,
                                               int Kr, int Nr, int Kp, int Np) {
  __shared__ float tile[64][65];
  int e = blockIdx.z;
  int k0 = blockIdx.x * 64, n0 = blockIdx.y * 64;
  int t = threadIdx.x;
  int cx = t & 63, ry = t >> 6;  // ry 0..3
  const float* sp = src + (size_t)e * Kr * Nr;
#pragma unroll
  for (int i = 0; i < 16; i++) {
    int k = k0 + ry + i * 4, n = n0 + cx;
    float v = (k < Kr && n < Nr) ? sp[(size_t)k * Nr + n] : 0.f;
    tile[ry + i * 4][cx] = v;
  }
  __syncthreads();
  unsigned short* dp = dst + (size_t)e * Np * Kp;
#pragma unroll
  for (int i = 0; i < 16; i++) {
    int nl = ry + i * 4, kl = cx;
    dp[(size_t)(n0 + nl) * Kp + k0 + kl] = f2bf(tile[kl][nl]);
  }
}

// ---------------- grouped GEMM v4: 128x64 tile, BK=32, async dbuf staging,
// XOR-swizzled LDS segments (seg ^= (row>>1)&3) -> 2-way banks (free).
// 2x2 waves, each wave 64x32 via 4x2 MFMA accs. One barrier per K-step.
// mid: out = relu(in @ W^T + b) -> bf16 (pad cols zeroed)
__global__ __launch_bounds__(256, 4) void k_gemm_mid(const unsigned short* __restrict__ in,
                                                  const unsigned short* __restrict__ wt,
                                                  const float* __restrict__ bias,
                                                  unsigned short* __restrict__ out,
                                                  const unsigned int* __restrict__ offsets,
                                                  const unsigned int* __restrict__ counts,
                                                  int KP, int NP, int NREAL) {
  int e = blockIdx.z;
  int n_e = (int)counts[e];
  if (n_e == 0) return;
  int base = (int)offsets[e];
  int bn = blockIdx.y;
  __shared__ unsigned short As[2][128 * 32];   // 2 x 8 KB
  __shared__ unsigned short Bs[2][64 * 32];    // 2 x 4 KB
  int t = threadIdx.x;
  int w = t >> 6, l = t & 63;
  int wm = w & 1, wn = w >> 1;
  int lr = l & 15, lq = l >> 4;
  int r_ = l >> 2, s_ = l & 3;                 // staging: row-in-16-chunk, segment
  int s2 = s_ ^ ((r_ >> 1) & 3);               // swizzled source segment
  int rsw = (lq ^ ((lr >> 1) & 3)) * 8;        // read-side swizzled offset (ushorts)

  unsigned short* dA0[2] = {&As[0][(w * 32) * 32], &As[1][(w * 32) * 32]};
  unsigned short* dA1[2] = {&As[0][(w * 32 + 16) * 32], &As[1][(w * 32 + 16) * 32]};
  unsigned short* dB[2]  = {&Bs[0][(w * 16) * 32], &Bs[1][(w * 16) * 32]};

  const unsigned short* bW = wt + (size_t)e * NP * KP;
  const unsigned short* bsrc = bW + (size_t)(bn * 64 + w * 16 + r_) * KP + s2 * 8;
  int nk = KP >> 5;

  for (int bm = blockIdx.x; bm * 128 < n_e; bm += gridDim.x) {
    int ra = bm * 128 + w * 32 + r_;       ra = (ra < n_e) ? ra : (n_e - 1);
    int rb = bm * 128 + w * 32 + 16 + r_;  rb = (rb < n_e) ? rb : (n_e - 1);
    const unsigned short* a0 = in + (size_t)(base + ra) * KP + s2 * 8;
    const unsigned short* a1 = in + (size_t)(base + rb) * KP + s2 * 8;
    const unsigned short* bq = bsrc;
    f32x4 acc[4][2];
#pragma unroll
    for (int i = 0; i < 4; i++)
#pragma unroll
      for (int j = 0; j < 2; j++) acc[i][j] = (f32x4){0.f, 0.f, 0.f, 0.f};

    ld_lds16(a0, dA0[0]); ld_lds16(a1, dA1[0]); ld_lds16(bq, dB[0]);
    a0 += 32; a1 += 32; bq += 32;

    for (int ks = 0; ks < nk; ks++) {
      int cb = ks & 1, nb = cb ^ 1;
      __syncthreads();   // drains vmcnt: buf[cb] ready; all reads of buf[nb] done last iter
      if (ks + 1 < nk) {
        ld_lds16(a0, dA0[nb]); ld_lds16(a1, dA1[nb]); ld_lds16(bq, dB[nb]);
        a0 += 32; a1 += 32; bq += 32;
      }
      s16x8 af[4], bf[2];
#pragma unroll
      for (int mt = 0; mt < 4; mt++) af[mt] = *(const s16x8*)&As[cb][(wm * 64 + mt * 16 + lr) * 32 + rsw];
#pragma unroll
      for (int nt = 0; nt < 2; nt++) bf[nt] = *(const s16x8*)&Bs[cb][(wn * 32 + nt * 16 + lr) * 32 + rsw];
#pragma unroll
      for (int mt = 0; mt < 4; mt++)
#pragma unroll
        for (int nt = 0; nt < 2; nt++)
          acc[mt][nt] = __builtin_amdgcn_mfma_f32_16x16x32_bf16(af[mt], bf[nt], acc[mt][nt], 0, 0, 0);
    }

#pragma unroll
    for (int nt = 0; nt < 2; nt++) {
      int col = bn * 64 + wn * 32 + nt * 16 + lr;
      bool cok = col < NREAL;
      float bv = cok ? bias[(size_t)e * NREAL + col] : 0.f;
#pragma unroll
      for (int mt = 0; mt < 4; mt++)
#pragma unroll
        for (int reg = 0; reg < 4; reg++) {
          int r = bm * 128 + wm * 64 + mt * 16 + lq * 4 + reg;
          if (r < n_e) {
            float v = cok ? fmaxf(acc[mt][nt][reg] + bv, 0.f) : 0.f;
            out[(size_t)(base + r) * NP + col] = f2bf(v);
          }
        }
    }
  }
}

// fin: scatter gate*(h3@W4+b4) into final output via f32 atomics (2 addends/elem)
__global__ __launch_bounds__(256, 4) void k_gemm_fin(const unsigned short* __restrict__ in,
                                                  const unsigned short* __restrict__ wt,
                                                  const float* __restrict__ bias,
                                                  float* __restrict__ dout,
                                                  const unsigned int* __restrict__ offsets,
                                                  const unsigned int* __restrict__ counts,
                                                  const int* __restrict__ slot_token,
                                                  const float* __restrict__ slot_gate) {
  const int KP = 1024, NP = 256;
  int e = blockIdx.z;
  int n_e = (int)counts[e];
  if (n_e == 0) return;
  int base = (int)offsets[e];
  int bn = blockIdx.y;
  __shared__ unsigned short As[2][128 * 32];
  __shared__ unsigned short Bs[2][64 * 32];
  int t = threadIdx.x;
  int w = t >> 6, l = t & 63;
  int wm = w & 1, wn = w >> 1;
  int lr = l & 15, lq = l >> 4;
  int r_ = l >> 2, s_ = l & 3;
  int s2 = s_ ^ ((r_ >> 1) & 3);
  int rsw = (lq ^ ((lr >> 1) & 3)) * 8;

  unsigned short* dA0[2] = {&As[0][(w * 32) * 32], &As[1][(w * 32) * 32]};
  unsigned short* dA1[2] = {&As[0][(w * 32 + 16) * 32], &As[1][(w * 32 + 16) * 32]};
  unsigned short* dB[2]  = {&Bs[0][(w * 16) * 32], &Bs[1][(w * 16) * 32]};

  const unsigned short* bW = wt + (size_t)e * NP * KP;
  const unsigned short* bsrc = bW + (size_t)(bn * 64 + w * 16 + r_) * KP + s2 * 8;
  int nk = KP >> 5;

  for (int bm = blockIdx.x; bm * 128 < n_e; bm += gridDim.x) {
    int ra = bm * 128 + w * 32 + r_;       ra = (ra < n_e) ? ra : (n_e - 1);
    int rb = bm * 128 + w * 32 + 16 + r_;  rb = (rb < n_e) ? rb : (n_e - 1);
    const unsigned short* a0 = in + (size_t)(base + ra) * KP + s2 * 8;
    const unsigned short* a1 = in + (size_t)(base + rb) * KP + s2 * 8;
    const unsigned short* bq = bsrc;
    f32x4 acc[4][2];
#pragma unroll
    for (int i = 0; i < 4; i++)
#pragma unroll
      for (int j = 0; j < 2; j++) acc[i][j] = (f32x4){0.f, 0.f, 0.f, 0.f};

    ld_lds16(a0, dA0[0]); ld_lds16(a1, dA1[0]); ld_lds16(bq, dB[0]);
    a0 += 32; a1 += 32; bq += 32;

    for (int ks = 0; ks < nk; ks++) {
      int cb = ks & 1, nb = cb ^ 1;
      __syncthreads();
      if (ks + 1 < nk) {
        ld_lds16(a0, dA0[nb]); ld_lds16(a1, dA1[nb]); ld_lds16(bq, dB[nb]);
        a0 += 32; a1 += 32; bq += 32;
      }
      s16x8 af[4], bf[2];
#pragma unroll
      for (int mt = 0; mt < 4; mt++) af[mt] = *(const s16x8*)&As[cb][(wm * 64 + mt * 16 + lr) * 32 + rsw];
#pragma unroll
      for (int nt = 0; nt < 2; nt++) bf[nt] = *(const s16x8*)&Bs[cb][(wn * 32 + nt * 16 + lr) * 32 + rsw];
#pragma unroll
      for (int mt = 0; mt < 4; mt++)
#pragma unroll
        for (int nt = 0; nt < 2; nt++)
          acc[mt][nt] = __builtin_amdgcn_mfma_f32_16x16x32_bf16(af[mt], bf[nt], acc[mt][nt], 0, 0, 0);
    }

#pragma unroll
    for (int mt = 0; mt < 4; mt++)
#pragma unroll
      for (int reg = 0; reg < 4; reg++) {
        int r = bm * 128 + wm * 64 + mt * 16 + lq * 4 + reg;
        if (r < n_e) {
          int gr = base + r;
          int tk = slot_token[gr];
          float g = slot_gate[gr];
#pragma unroll
          for (int nt = 0; nt < 2; nt++) {
            int col = bn * 64 + wn * 32 + nt * 16 + lr;
            float v = acc[mt][nt][reg] + bias[(size_t)e * 256 + col];
            atomicAdd(&dout[(size_t)tk * D_OUT + col], g * v);
          }
        }
      }
  }
}

extern "C" void kernel_launch(void* const* d_in, const int* in_sizes, int n_in,
                              void* d_out, int out_size, void* d_ws, size_t ws_size,
                              hipStream_t stream) {
  const float* x    = (const float*)d_in[0];
  const float* nois = (const float*)d_in[1];
  const float* Wr   = (const float*)d_in[2];
  const float* W1   = (const float*)d_in[3];
  const float* b1   = (const float*)d_in[4];
  const float* W2   = (const float*)d_in[5];
  const float* b2   = (const float*)d_in[6];
  const float* W3   = (const float*)d_in[7];
  const float* b3   = (const float*)d_in[8];
  const float* W4   = (const float*)d_in[9];
  const float* b4   = (const float*)d_in[10];
  float* out = (float*)d_out;

  char* w = (char*)d_ws;
  unsigned short* actA = (unsigned short*)(w + 0);             // 32768*1024 bf16 = 67108864 B
  unsigned short* actB = (unsigned short*)(w + 67108864);      // 32768*512 bf16  = 33554432 B
  unsigned short* Wt   = (unsigned short*)(w + 100663296);     // <=16*512*1024 bf16 = 16777216 B
  int*            slot_token = (int*)(w + 117440512);          // 131072 B
  float*          slot_gate  = (float*)(w + 117571584);        // 131072 B
  TokenRec*       te         = (TokenRec*)(w + 117702656);     // 262144 B
  unsigned int*   counts  = (unsigned int*)(w + 117964800);
  unsigned int*   cursor  = (unsigned int*)(w + 117964864);
  unsigned int*   offsets = (unsigned int*)(w + 117964928);
  // transient (dead before GEMM L1 writes actA): overlay on actA region
  float*          sel_buf  = (float*)(w + 0);                  // 16384*16 f32 = 1 MB
  float*          partials = (float*)(w + 1048576);            // 16*32 f32 = 2 KB

  float* sel_out  = out + (size_t)S_TOK * D_OUT;
  float* loss_out = out + (size_t)S_TOK * D_OUT + (size_t)S_TOK * E_EXP;

  k_init<<<dim3((S_TOK * D_OUT) / 1024), dim3(256), 0, stream>>>(out, cursor);
  k_router<<<dim3(S_TOK / 16), dim3(256), 0, stream>>>(x, nois, Wr, sel_out, sel_buf, te);
  k_stats<<<dim3(16), dim3(256), 0, stream>>>(sel_buf, te, partials);
  k_prefix_loss<<<dim3(1), dim3(64), 0, stream>>>(partials, counts, offsets, loss_out);
  k_listbuild<<<dim3(16), dim3(256), 0, stream>>>(te, offsets, cursor, slot_token, slot_gate);
  k_gather<<<dim3((2 * S_TOK * 128) / 256), dim3(256), 0, stream>>>(x, slot_token, actB);

  // Layer 1: [*,512] @ [512,500] -> relu -> actA (stride 512)
  k_convw<<<dim3(8, 8, E_EXP), dim3(256), 0, stream>>>(W1, Wt, 512, H1D, 512, 512);
  k_gemm_mid<<<dim3(24, 8, E_EXP), dim3(256), 0, stream>>>(actB, Wt, b1, actA, offsets, counts, 512, 512, H1D);
  // Layer 2: [*,500] @ [500,500] -> relu -> actB (stride 512)
  k_convw<<<dim3(8, 8, E_EXP), dim3(256), 0, stream>>>(W2, Wt, H1D, H2D, 512, 512);
  k_gemm_mid<<<dim3(24, 8, E_EXP), dim3(256), 0, stream>>>(actA, Wt, b2, actB, offsets, counts, 512, 512, H2D);
  // Layer 3: [*,500] @ [500,1000] -> relu -> actA (stride 1024)
  k_convw<<<dim3(8, 16, E_EXP), dim3(256), 0, stream>>>(W3, Wt, H2D, H3D, 512, 1024);
  k_gemm_mid<<<dim3(24, 16, E_EXP), dim3(256), 0, stream>>>(actB, Wt, b3, actA, offsets, counts, 512, 1024, H3D);
  // Layer 4: [*,1000] @ [1000,256] -> scatter gate-weighted into out
  k_convw<<<dim3(16, 4, E_EXP), dim3(256), 0, stream>>>(W4, Wt, H3D, D_OUT, 1024, 256);
  k_gemm_fin<<<dim3(24, 4, E_EXP), dim3(256), 0, stream>>>(actA, Wt, b4, out, offsets, counts, slot_token, slot_gate);

  (void)in_sizes; (void)n_in; (void)out_size; (void)ws_size;
}

// Round 6
// 485.816 us; speedup vs baseline: 1.3078x; 1.0436x over previous
//
#include <hip/hip_runtime.h>
#include <stdint.h>

#define S_TOK 16384
#define M_DIM 512
#define E_EXP 16
#define D_OUT 256
#define H1D 500
#define H2D 500
#define H3D 1000

typedef float f32x4 __attribute__((ext_vector_type(4)));
typedef short s16x8 __attribute__((ext_vector_type(8)));

__device__ __forceinline__ unsigned short f2bf(float f) {
  unsigned int u = __float_as_uint(f);
  u += 0x7fffu + ((u >> 16) & 1u);
  return (unsigned short)(u >> 16);
}

// async global->LDS, 16B per lane; LDS dest = wave-uniform base + lane*16
__device__ __forceinline__ void ld_lds16(const unsigned short* g, unsigned short* l) {
  __builtin_amdgcn_global_load_lds(
      (const __attribute__((address_space(1))) unsigned int*)(const void*)g,
      (__attribute__((address_space(3))) unsigned int*)(void*)l, 16, 0, 0);
}

struct TokenRec { int i1, i2; float g1, g2; };

// ---------------- router: lane-parallel experts, f64 accum, no global atomics ------
__global__ __launch_bounds__(256) void k_router(const float* __restrict__ x,
                                                const float* __restrict__ noise,
                                                const float* __restrict__ Wr,
                                                float* __restrict__ sel_out,
                                                float* __restrict__ sel_buf,
                                                TokenRec* __restrict__ te) {
  __shared__ float wr[E_EXP * 516];   // pad 516: 2-way LDS aliasing only (free)
  int t = threadIdx.x;
  for (int i = t; i < E_EXP * M_DIM; i += 256) {
    int e = i >> 9, m = i & 511;
    wr[e * 516 + m] = Wr[i];
  }
  __syncthreads();

  int wv = t >> 6, l = t & 63;
  int e = l & 15, tg = l >> 4;                  // expert, token-slot in wave
  int s = blockIdx.x * 16 + wv * 4 + tg;        // token id

  const float* xr = x + (size_t)s * M_DIM;
  const float* wre = &wr[e * 516];
  double a0 = 0.0, a1 = 0.0, a2 = 0.0, a3 = 0.0;
#pragma unroll 4
  for (int m = 0; m < M_DIM; m += 4) {
    f32x4 xv = *(const f32x4*)(xr + m);
    f32x4 wv4 = *(const f32x4*)(wre + m);
    a0 += (double)xv.x * (double)wv4.x;
    a1 += (double)xv.y * (double)wv4.y;
    a2 += (double)xv.z * (double)wv4.z;
    a3 += (double)xv.w * (double)wv4.w;
  }
  double a = (a0 + a1) + (a2 + a3);
  a += (double)noise[(size_t)s * E_EXP + e];

  double mx = a;
#pragma unroll
  for (int off = 8; off >= 1; off >>= 1) { double o = __shfl_xor(mx, off, 64); mx = (o > mx) ? o : mx; }
  double p = exp(a - mx);
  double sum = p;
#pragma unroll
  for (int off = 8; off >= 1; off >>= 1) sum += __shfl_xor(sum, off, 64);
  sel_buf[(size_t)s * E_EXP + e] = (float)(p / sum);

  unsigned long long pb = __double_as_longlong(p);
  unsigned long long key = (pb & ~0xFFull) | (unsigned long long)(255 - e);
  unsigned long long k1 = key;
#pragma unroll
  for (int off = 8; off >= 1; off >>= 1) { unsigned long long o = __shfl_xor(k1, off, 64); k1 = (o > k1) ? o : k1; }
  int i1 = 255 - (int)(k1 & 0xFFull);
  unsigned long long key2 = (e == i1) ? 0ull : key;
  unsigned long long k2 = key2;
#pragma unroll
  for (int off = 8; off >= 1; off >>= 1) { unsigned long long o = __shfl_xor(k2, off, 64); k2 = (o > k2) ? o : k2; }
  int i2 = 255 - (int)(k2 & 0xFFull);

  double p1 = __shfl(p, tg * 16 + i1, 64);
  double p2 = __shfl(p, tg * 16 + i2, 64);

  sel_out[(size_t)s * E_EXP + e] = (e == i1 || e == i2) ? 1.f : 0.f;
  if (e == 0) {
    double inv = 1.0 / (p1 + p2);
    TokenRec r; r.i1 = i1; r.i2 = i2; r.g1 = (float)(p1 * inv); r.g2 = (float)(p2 * inv);
    te[s] = r;
  }
}

// ---------------- stats: per-block proxy partial sums + histogram ----------------
__global__ __launch_bounds__(256) void k_stats(const float* __restrict__ sel_buf,
                                               const TokenRec* __restrict__ te,
                                               float* __restrict__ partials) {  // [16][32]
  __shared__ float psum[256];
  __shared__ unsigned int hist[E_EXP];
  int t = threadIdx.x, b = blockIdx.x;
  if (t < E_EXP) hist[t] = 0u;
  __syncthreads();
  int e = t & 15, rg = t >> 4;
  int base = b * 1024;
  float acc = 0.f;
#pragma unroll 4
  for (int i = 0; i < 64; i++)
    acc += sel_buf[(size_t)(base + i * 16 + rg) * E_EXP + e];
  for (int i = t; i < 1024; i += 256) {
    TokenRec r = te[base + i];
    atomicAdd(&hist[r.i1], 1u);   // LDS atomics
    atomicAdd(&hist[r.i2], 1u);
  }
  psum[t] = acc;
  __syncthreads();
  if (t < E_EXP) {
    float v = 0.f;
#pragma unroll
    for (int rg2 = 0; rg2 < 16; rg2++) v += psum[rg2 * 16 + t];
    partials[b * 32 + t] = v;
    partials[b * 32 + 16 + t] = (float)hist[t];
  }
}

// ---------------- reduce partials -> counts/offsets + balance loss + cursor init ------
__global__ void k_prefix_loss(const float* __restrict__ partials,
                              unsigned int* __restrict__ counts,
                              unsigned int* __restrict__ offsets,
                              unsigned int* __restrict__ cursor,
                              float* __restrict__ out_loss) {
  __shared__ float pr[E_EXP];
  __shared__ unsigned int cn[E_EXP];
  int t = threadIdx.x;
  if (t < E_EXP) {
    float p = 0.f, c = 0.f;
    for (int b = 0; b < 16; b++) { p += partials[b * 32 + t]; c += partials[b * 32 + 16 + t]; }
    pr[t] = p; cn[t] = (unsigned int)(c + 0.5f);
    cursor[t] = 0u;
  }
  __syncthreads();
  if (t == 0) {
    unsigned int acc = 0; float ls = 0.f;
    for (int e = 0; e < E_EXP; e++) {
      counts[e] = cn[e];
      offsets[e] = acc;
      acc += cn[e];
      ls += pr[e] * (float)cn[e];
    }
    out_loss[0] = ls * ((float)E_EXP / ((float)S_TOK * (float)S_TOK));
    out_loss[1] = 0.f;
  }
}

// ---------------- listbuild: block-level reservation + inverse map ----------------
__global__ __launch_bounds__(256) void k_listbuild(const TokenRec* __restrict__ te,
                                                   const unsigned int* __restrict__ offsets,
                                                   unsigned int* __restrict__ cursor,
                                                   int* __restrict__ slot_token,
                                                   float* __restrict__ slot_gate,
                                                   int* __restrict__ tok_slot) {
  __shared__ unsigned int lhist[E_EXP];
  __shared__ unsigned int lbase[E_EXP];
  __shared__ unsigned int lcur[E_EXP];
  int t = threadIdx.x, b = blockIdx.x;
  int base = b * 1024;
  if (t < E_EXP) lhist[t] = 0u;
  __syncthreads();
  for (int i = t; i < 1024; i += 256) {
    TokenRec r = te[base + i];
    atomicAdd(&lhist[r.i1], 1u);
    atomicAdd(&lhist[r.i2], 1u);
  }
  __syncthreads();
  if (t < E_EXP) {
    lbase[t] = offsets[t] + atomicAdd(&cursor[t], lhist[t]);
    lcur[t] = 0u;
  }
  __syncthreads();
  for (int i = t; i < 1024; i += 256) {
    int s = base + i;
    TokenRec r = te[s];
    unsigned int p1 = atomicAdd(&lcur[r.i1], 1u);
    int sl1 = (int)(lbase[r.i1] + p1);
    slot_token[sl1] = s; slot_gate[sl1] = r.g1;
    unsigned int p2 = atomicAdd(&lcur[r.i2], 1u);
    int sl2 = (int)(lbase[r.i2] + p2);
    slot_token[sl2] = s; slot_gate[sl2] = r.g2;
    tok_slot[2 * s] = sl1;
    tok_slot[2 * s + 1] = sl2;
  }
}

// ---------------- gather x rows -> bf16 compact activations ----------------
__global__ __launch_bounds__(256) void k_gather(const float* __restrict__ x,
                                                const int* __restrict__ slot_token,
                                                unsigned short* __restrict__ xg) {
  int idx = blockIdx.x * 256 + threadIdx.x;  // 32768*128 total
  int row = idx >> 7, q = idx & 127;
  int tkn = slot_token[row];
  f32x4 v = *(const f32x4*)&x[(size_t)tkn * M_DIM + q * 4];
  ushort4 o;
  o.x = f2bf(v.x); o.y = f2bf(v.y); o.z = f2bf(v.z); o.w = f2bf(v.w);
  *(ushort4*)&xg[(size_t)row * 512 + q * 4] = o;
}

// ---------------- weight convert: f32 [E][Kr][Nr] -> bf16 transposed padded [E][Np][Kp]
__global__ __launch_bounds__(256) void k_convw(const float* __restrict__ src,
                                               unsigned short* __restrict__ dst,
                                               int Kr, int Nr, int Kp, int Np) {
  __shared__ float tile[64][65];
  int e = blockIdx.z;
  int k0 = blockIdx.x * 64, n0 = blockIdx.y * 64;
  int t = threadIdx.x;
  int cx = t & 63, ry = t >> 6;  // ry 0..3
  const float* sp = src + (size_t)e * Kr * Nr;
#pragma unroll
  for (int i = 0; i < 16; i++) {
    int k = k0 + ry + i * 4, n = n0 + cx;
    float v = (k < Kr && n < Nr) ? sp[(size_t)k * Nr + n] : 0.f;
    tile[ry + i * 4][cx] = v;
  }
  __syncthreads();
  unsigned short* dp = dst + (size_t)e * Np * Kp;
#pragma unroll
  for (int i = 0; i < 16; i++) {
    int nl = ry + i * 4, kl = cx;
    dp[(size_t)(n0 + nl) * Kp + k0 + kl] = f2bf(tile[kl][nl]);
  }
}

// ---------------- grouped GEMM v4: 128x64 tile, BK=32, async dbuf staging,
// XOR-swizzled LDS segments -> 2-way banks (free). 2x2 waves, 4x2 accs/wave.
// mid: out = relu(in @ W^T + b) -> bf16 (pad cols zeroed)
__global__ __launch_bounds__(256, 4) void k_gemm_mid(const unsigned short* __restrict__ in,
                                                  const unsigned short* __restrict__ wt,
                                                  const float* __restrict__ bias,
                                                  unsigned short* __restrict__ out,
                                                  const unsigned int* __restrict__ offsets,
                                                  const unsigned int* __restrict__ counts,
                                                  int KP, int NP, int NREAL) {
  int e = blockIdx.z;
  int n_e = (int)counts[e];
  if (n_e == 0) return;
  int base = (int)offsets[e];
  int bn = blockIdx.y;
  __shared__ unsigned short As[2][128 * 32];   // 2 x 8 KB
  __shared__ unsigned short Bs[2][64 * 32];    // 2 x 4 KB
  int t = threadIdx.x;
  int w = t >> 6, l = t & 63;
  int wm = w & 1, wn = w >> 1;
  int lr = l & 15, lq = l >> 4;
  int r_ = l >> 2, s_ = l & 3;                 // staging: row-in-16-chunk, segment
  int s2 = s_ ^ ((r_ >> 1) & 3);               // swizzled source segment
  int rsw = (lq ^ ((lr >> 1) & 3)) * 8;        // read-side swizzled offset (ushorts)

  unsigned short* dA0[2] = {&As[0][(w * 32) * 32], &As[1][(w * 32) * 32]};
  unsigned short* dA1[2] = {&As[0][(w * 32 + 16) * 32], &As[1][(w * 32 + 16) * 32]};
  unsigned short* dB[2]  = {&Bs[0][(w * 16) * 32], &Bs[1][(w * 16) * 32]};

  const unsigned short* bW = wt + (size_t)e * NP * KP;
  const unsigned short* bsrc = bW + (size_t)(bn * 64 + w * 16 + r_) * KP + s2 * 8;
  int nk = KP >> 5;

  for (int bm = blockIdx.x; bm * 128 < n_e; bm += gridDim.x) {
    int ra = bm * 128 + w * 32 + r_;       ra = (ra < n_e) ? ra : (n_e - 1);
    int rb = bm * 128 + w * 32 + 16 + r_;  rb = (rb < n_e) ? rb : (n_e - 1);
    const unsigned short* a0 = in + (size_t)(base + ra) * KP + s2 * 8;
    const unsigned short* a1 = in + (size_t)(base + rb) * KP + s2 * 8;
    const unsigned short* bq = bsrc;
    f32x4 acc[4][2];
#pragma unroll
    for (int i = 0; i < 4; i++)
#pragma unroll
      for (int j = 0; j < 2; j++) acc[i][j] = (f32x4){0.f, 0.f, 0.f, 0.f};

    ld_lds16(a0, dA0[0]); ld_lds16(a1, dA1[0]); ld_lds16(bq, dB[0]);
    a0 += 32; a1 += 32; bq += 32;

    for (int ks = 0; ks < nk; ks++) {
      int cb = ks & 1, nb = cb ^ 1;
      __syncthreads();   // drains vmcnt: buf[cb] ready; all reads of buf[nb] done last iter
      if (ks + 1 < nk) {
        ld_lds16(a0, dA0[nb]); ld_lds16(a1, dA1[nb]); ld_lds16(bq, dB[nb]);
        a0 += 32; a1 += 32; bq += 32;
      }
      s16x8 af[4], bf[2];
#pragma unroll
      for (int mt = 0; mt < 4; mt++) af[mt] = *(const s16x8*)&As[cb][(wm * 64 + mt * 16 + lr) * 32 + rsw];
#pragma unroll
      for (int nt = 0; nt < 2; nt++) bf[nt] = *(const s16x8*)&Bs[cb][(wn * 32 + nt * 16 + lr) * 32 + rsw];
#pragma unroll
      for (int mt = 0; mt < 4; mt++)
#pragma unroll
        for (int nt = 0; nt < 2; nt++)
          acc[mt][nt] = __builtin_amdgcn_mfma_f32_16x16x32_bf16(af[mt], bf[nt], acc[mt][nt], 0, 0, 0);
    }

#pragma unroll
    for (int nt = 0; nt < 2; nt++) {
      int col = bn * 64 + wn * 32 + nt * 16 + lr;
      bool cok = col < NREAL;
      float bv = cok ? bias[(size_t)e * NREAL + col] : 0.f;
#pragma unroll
      for (int mt = 0; mt < 4; mt++)
#pragma unroll
        for (int reg = 0; reg < 4; reg++) {
          int r = bm * 128 + wm * 64 + mt * 16 + lq * 4 + reg;
          if (r < n_e) {
            float v = cok ? fmaxf(acc[mt][nt][reg] + bv, 0.f) : 0.f;
            out[(size_t)(base + r) * NP + col] = f2bf(v);
          }
        }
    }
  }
}

// fin: eo[slot] = gate * (h3 @ W4 + b4); plain coalesced stores, no atomics
__global__ __launch_bounds__(256, 4) void k_gemm_fin(const unsigned short* __restrict__ in,
                                                  const unsigned short* __restrict__ wt,
                                                  const float* __restrict__ bias,
                                                  float* __restrict__ eo,
                                                  const unsigned int* __restrict__ offsets,
                                                  const unsigned int* __restrict__ counts,
                                                  const float* __restrict__ slot_gate) {
  const int KP = 1024, NP = 256;
  int e = blockIdx.z;
  int n_e = (int)counts[e];
  if (n_e == 0) return;
  int base = (int)offsets[e];
  int bn = blockIdx.y;
  __shared__ unsigned short As[2][128 * 32];
  __shared__ unsigned short Bs[2][64 * 32];
  int t = threadIdx.x;
  int w = t >> 6, l = t & 63;
  int wm = w & 1, wn = w >> 1;
  int lr = l & 15, lq = l >> 4;
  int r_ = l >> 2, s_ = l & 3;
  int s2 = s_ ^ ((r_ >> 1) & 3);
  int rsw = (lq ^ ((lr >> 1) & 3)) * 8;

  unsigned short* dA0[2] = {&As[0][(w * 32) * 32], &As[1][(w * 32) * 32]};
  unsigned short* dA1[2] = {&As[0][(w * 32 + 16) * 32], &As[1][(w * 32 + 16) * 32]};
  unsigned short* dB[2]  = {&Bs[0][(w * 16) * 32], &Bs[1][(w * 16) * 32]};

  const unsigned short* bW = wt + (size_t)e * NP * KP;
  const unsigned short* bsrc = bW + (size_t)(bn * 64 + w * 16 + r_) * KP + s2 * 8;
  int nk = KP >> 5;

  for (int bm = blockIdx.x; bm * 128 < n_e; bm += gridDim.x) {
    int ra = bm * 128 + w * 32 + r_;       ra = (ra < n_e) ? ra : (n_e - 1);
    int rb = bm * 128 + w * 32 + 16 + r_;  rb = (rb < n_e) ? rb : (n_e - 1);
    const unsigned short* a0 = in + (size_t)(base + ra) * KP + s2 * 8;
    const unsigned short* a1 = in + (size_t)(base + rb) * KP + s2 * 8;
    const unsigned short* bq = bsrc;
    f32x4 acc[4][2];
#pragma unroll
    for (int i = 0; i < 4; i++)
#pragma unroll
      for (int j = 0; j < 2; j++) acc[i][j] = (f32x4){0.f, 0.f, 0.f, 0.f};

    ld_lds16(a0, dA0[0]); ld_lds16(a1, dA1[0]); ld_lds16(bq, dB[0]);
    a0 += 32; a1 += 32; bq += 32;

    for (int ks = 0; ks < nk; ks++) {
      int cb = ks & 1, nb = cb ^ 1;
      __syncthreads();
      if (ks + 1 < nk) {
        ld_lds16(a0, dA0[nb]); ld_lds16(a1, dA1[nb]); ld_lds16(bq, dB[nb]);
        a0 += 32; a1 += 32; bq += 32;
      }
      s16x8 af[4], bf[2];
#pragma unroll
      for (int mt = 0; mt < 4; mt++) af[mt] = *(const s16x8*)&As[cb][(wm * 64 + mt * 16 + lr) * 32 + rsw];
#pragma unroll
      for (int nt = 0; nt < 2; nt++) bf[nt] = *(const s16x8*)&Bs[cb][(wn * 32 + nt * 16 + lr) * 32 + rsw];
#pragma unroll
      for (int mt = 0; mt < 4; mt++)
#pragma unroll
        for (int nt = 0; nt < 2; nt++)
          acc[mt][nt] = __builtin_amdgcn_mfma_f32_16x16x32_bf16(af[mt], bf[nt], acc[mt][nt], 0, 0, 0);
    }

#pragma unroll
    for (int mt = 0; mt < 4; mt++)
#pragma unroll
      for (int reg = 0; reg < 4; reg++) {
        int r = bm * 128 + wm * 64 + mt * 16 + lq * 4 + reg;
        if (r < n_e) {
          int gr = base + r;
          float g = slot_gate[gr];
#pragma unroll
          for (int nt = 0; nt < 2; nt++) {
            int col = bn * 64 + wn * 32 + nt * 16 + lr;
            eo[(size_t)gr * NP + col] = g * (acc[mt][nt][reg] + bias[(size_t)e * 256 + col]);
          }
        }
      }
  }
}

// ---------------- combine: out[s] = eo[sl1(s)] + eo[sl2(s)] ----------------
__global__ __launch_bounds__(256) void k_combine(const float* __restrict__ eo,
                                                 const int* __restrict__ tok_slot,
                                                 float* __restrict__ out) {
  int idx = blockIdx.x * 256 + threadIdx.x;   // S*64 threads, 4 cols each
  int s = idx >> 6, q = idx & 63;
  int sl1 = tok_slot[2 * s], sl2 = tok_slot[2 * s + 1];
  f32x4 v1 = *(const f32x4*)&eo[(size_t)sl1 * D_OUT + q * 4];
  f32x4 v2 = *(const f32x4*)&eo[(size_t)sl2 * D_OUT + q * 4];
  *(f32x4*)&out[(size_t)s * D_OUT + q * 4] = v1 + v2;
}

extern "C" void kernel_launch(void* const* d_in, const int* in_sizes, int n_in,
                              void* d_out, int out_size, void* d_ws, size_t ws_size,
                              hipStream_t stream) {
  const float* x    = (const float*)d_in[0];
  const float* nois = (const float*)d_in[1];
  const float* Wr   = (const float*)d_in[2];
  const float* W1   = (const float*)d_in[3];
  const float* b1   = (const float*)d_in[4];
  const float* W2   = (const float*)d_in[5];
  const float* b2   = (const float*)d_in[6];
  const float* W3   = (const float*)d_in[7];
  const float* b3   = (const float*)d_in[8];
  const float* W4   = (const float*)d_in[9];
  const float* b4   = (const float*)d_in[10];
  float* out = (float*)d_out;

  char* w = (char*)d_ws;
  unsigned short* actA = (unsigned short*)(w + 0);             // 32768*1024 bf16 = 67108864 B
  unsigned short* actB = (unsigned short*)(w + 67108864);      // 32768*512 bf16  = 33554432 B
  unsigned short* Wt   = (unsigned short*)(w + 100663296);     // <=16*512*1024 bf16 = 16777216 B
  int*            slot_token = (int*)(w + 117440512);          // 131072 B
  float*          slot_gate  = (float*)(w + 117571584);        // 131072 B
  TokenRec*       te         = (TokenRec*)(w + 117702656);     // 262144 B
  unsigned int*   counts  = (unsigned int*)(w + 117964800);
  unsigned int*   cursor  = (unsigned int*)(w + 117964864);
  unsigned int*   offsets = (unsigned int*)(w + 117964928);
  int*            tok_slot = (int*)(w + 117965056);            // 131072 B
  // transient (dead before GEMM L1 writes actA): overlay on actA region
  float*          sel_buf  = (float*)(w + 0);                  // 16384*16 f32 = 1 MB
  float*          partials = (float*)(w + 1048576);            // 16*32 f32 = 2 KB
  // eo overlays actB (dead after L3 GEMM consumes it): 32768*256 f32 = 33554432 B
  float*          eo       = (float*)(w + 67108864);

  float* sel_out  = out + (size_t)S_TOK * D_OUT;
  float* loss_out = out + (size_t)S_TOK * D_OUT + (size_t)S_TOK * E_EXP;

  k_router<<<dim3(S_TOK / 16), dim3(256), 0, stream>>>(x, nois, Wr, sel_out, sel_buf, te);
  k_stats<<<dim3(16), dim3(256), 0, stream>>>(sel_buf, te, partials);
  k_prefix_loss<<<dim3(1), dim3(64), 0, stream>>>(partials, counts, offsets, cursor, loss_out);
  k_listbuild<<<dim3(16), dim3(256), 0, stream>>>(te, offsets, cursor, slot_token, slot_gate, tok_slot);
  k_gather<<<dim3((2 * S_TOK * 128) / 256), dim3(256), 0, stream>>>(x, slot_token, actB);

  // Layer 1: [*,512] @ [512,500] -> relu -> actA (stride 512)
  k_convw<<<dim3(8, 8, E_EXP), dim3(256), 0, stream>>>(W1, Wt, 512, H1D, 512, 512);
  k_gemm_mid<<<dim3(24, 8, E_EXP), dim3(256), 0, stream>>>(actB, Wt, b1, actA, offsets, counts, 512, 512, H1D);
  // Layer 2: [*,500] @ [500,500] -> relu -> actB (stride 512)
  k_convw<<<dim3(8, 8, E_EXP), dim3(256), 0, stream>>>(W2, Wt, H1D, H2D, 512, 512);
  k_gemm_mid<<<dim3(24, 8, E_EXP), dim3(256), 0, stream>>>(actA, Wt, b2, actB, offsets, counts, 512, 512, H2D);
  // Layer 3: [*,500] @ [500,1000] -> relu -> actA (stride 1024)
  k_convw<<<dim3(8, 16, E_EXP), dim3(256), 0, stream>>>(W3, Wt, H2D, H3D, 512, 1024);
  k_gemm_mid<<<dim3(24, 16, E_EXP), dim3(256), 0, stream>>>(actB, Wt, b3, actA, offsets, counts, 512, 1024, H3D);
  // Layer 4: [*,1000] @ [1000,256] -> eo[slot] = gate*(h3@W4+b4)   (eo overlays actB)
  k_convw<<<dim3(16, 4, E_EXP), dim3(256), 0, stream>>>(W4, Wt, H3D, D_OUT, 1024, 256);
  k_gemm_fin<<<dim3(24, 4, E_EXP), dim3(256), 0, stream>>>(actA, Wt, b4, eo, offsets, counts, slot_gate);
  // Combine: out[s] = eo[sl1] + eo[sl2]
  k_combine<<<dim3(S_TOK * 64 / 256), dim3(256), 0, stream>>>(eo, tok_slot, out);

  (void)in_sizes; (void)n_in; (void)out_size; (void)ws_size;
}

// Round 8
// 385.701 us; speedup vs baseline: 1.6473x; 1.2596x over previous
//
#include <hip/hip_runtime.h>
#include <stdint.h>

#define S_TOK 16384
#define M_DIM 512
#define E_EXP 16
#define D_OUT 256
#define H1D 500
#define H2D 500
#define H3D 1000

typedef float f32x4 __attribute__((ext_vector_type(4)));
typedef long lx2 __attribute__((ext_vector_type(2)));   // 16 B = two fp8 fragments
typedef int i32x2 __attribute__((ext_vector_type(2)));

template <bool HI>
__device__ __forceinline__ int pk8(float a, float b, int old) {
  return __builtin_amdgcn_cvt_pk_fp8_f32(a, b, old, HI);
}
__device__ __forceinline__ unsigned char f2fp8(float f) {
  return (unsigned char)(__builtin_amdgcn_cvt_pk_fp8_f32(f, 0.f, 0, false) & 0xff);
}

// async global->LDS, 16B per lane; LDS dest = wave-uniform base + lane*16
__device__ __forceinline__ void ld_lds16(const unsigned char* g, unsigned char* l) {
  __builtin_amdgcn_global_load_lds(
      (const __attribute__((address_space(1))) unsigned int*)(const void*)g,
      (__attribute__((address_space(3))) unsigned int*)(void*)l, 16, 0, 0);
}

struct TokenRec { int i1, i2; float g1, g2; };

// ---------------- router: lane-parallel experts, f64 accum, no global atomics ------
__global__ __launch_bounds__(256) void k_router(const float* __restrict__ x,
                                                const float* __restrict__ noise,
                                                const float* __restrict__ Wr,
                                                float* __restrict__ sel_out,
                                                float* __restrict__ sel_buf,
                                                TokenRec* __restrict__ te) {
  __shared__ float wr[E_EXP * 516];   // pad 516: 2-way LDS aliasing only (free)
  int t = threadIdx.x;
  for (int i = t; i < E_EXP * M_DIM; i += 256) {
    int e = i >> 9, m = i & 511;
    wr[e * 516 + m] = Wr[i];
  }
  __syncthreads();

  int wv = t >> 6, l = t & 63;
  int e = l & 15, tg = l >> 4;
  int s = blockIdx.x * 16 + wv * 4 + tg;

  const float* xr = x + (size_t)s * M_DIM;
  const float* wre = &wr[e * 516];
  double a0 = 0.0, a1 = 0.0, a2 = 0.0, a3 = 0.0;
#pragma unroll 4
  for (int m = 0; m < M_DIM; m += 4) {
    f32x4 xv = *(const f32x4*)(xr + m);
    f32x4 wv4 = *(const f32x4*)(wre + m);
    a0 += (double)xv.x * (double)wv4.x;
    a1 += (double)xv.y * (double)wv4.y;
    a2 += (double)xv.z * (double)wv4.z;
    a3 += (double)xv.w * (double)wv4.w;
  }
  double a = (a0 + a1) + (a2 + a3);
  a += (double)noise[(size_t)s * E_EXP + e];

  double mx = a;
#pragma unroll
  for (int off = 8; off >= 1; off >>= 1) { double o = __shfl_xor(mx, off, 64); mx = (o > mx) ? o : mx; }
  double p = exp(a - mx);
  double sum = p;
#pragma unroll
  for (int off = 8; off >= 1; off >>= 1) sum += __shfl_xor(sum, off, 64);
  sel_buf[(size_t)s * E_EXP + e] = (float)(p / sum);

  unsigned long long pb = __double_as_longlong(p);
  unsigned long long key = (pb & ~0xFFull) | (unsigned long long)(255 - e);
  unsigned long long k1 = key;
#pragma unroll
  for (int off = 8; off >= 1; off >>= 1) { unsigned long long o = __shfl_xor(k1, off, 64); k1 = (o > k1) ? o : k1; }
  int i1 = 255 - (int)(k1 & 0xFFull);
  unsigned long long key2 = (e == i1) ? 0ull : key;
  unsigned long long k2 = key2;
#pragma unroll
  for (int off = 8; off >= 1; off >>= 1) { unsigned long long o = __shfl_xor(k2, off, 64); k2 = (o > k2) ? o : k2; }
  int i2 = 255 - (int)(k2 & 0xFFull);

  double p1 = __shfl(p, tg * 16 + i1, 64);
  double p2 = __shfl(p, tg * 16 + i2, 64);

  sel_out[(size_t)s * E_EXP + e] = (e == i1 || e == i2) ? 1.f : 0.f;
  if (e == 0) {
    double inv = 1.0 / (p1 + p2);
    TokenRec r; r.i1 = i1; r.i2 = i2; r.g1 = (float)(p1 * inv); r.g2 = (float)(p2 * inv);
    te[s] = r;
  }
}

// ---------------- stats: per-block proxy partial sums + histogram ----------------
__global__ __launch_bounds__(256) void k_stats(const float* __restrict__ sel_buf,
                                               const TokenRec* __restrict__ te,
                                               float* __restrict__ partials) {  // [16][32]
  __shared__ float psum[256];
  __shared__ unsigned int hist[E_EXP];
  int t = threadIdx.x, b = blockIdx.x;
  if (t < E_EXP) hist[t] = 0u;
  __syncthreads();
  int e = t & 15, rg = t >> 4;
  int base = b * 1024;
  float acc = 0.f;
#pragma unroll 4
  for (int i = 0; i < 64; i++)
    acc += sel_buf[(size_t)(base + i * 16 + rg) * E_EXP + e];
  for (int i = t; i < 1024; i += 256) {
    TokenRec r = te[base + i];
    atomicAdd(&hist[r.i1], 1u);
    atomicAdd(&hist[r.i2], 1u);
  }
  psum[t] = acc;
  __syncthreads();
  if (t < E_EXP) {
    float v = 0.f;
#pragma unroll
    for (int rg2 = 0; rg2 < 16; rg2++) v += psum[rg2 * 16 + t];
    partials[b * 32 + t] = v;
    partials[b * 32 + 16 + t] = (float)hist[t];
  }
}

// ---------------- reduce partials -> counts/offsets + balance loss + cursor init ------
__global__ void k_prefix_loss(const float* __restrict__ partials,
                              unsigned int* __restrict__ counts,
                              unsigned int* __restrict__ offsets,
                              unsigned int* __restrict__ cursor,
                              float* __restrict__ out_loss) {
  __shared__ float pr[E_EXP];
  __shared__ unsigned int cn[E_EXP];
  int t = threadIdx.x;
  if (t < E_EXP) {
    float p = 0.f, c = 0.f;
    for (int b = 0; b < 16; b++) { p += partials[b * 32 + t]; c += partials[b * 32 + 16 + t]; }
    pr[t] = p; cn[t] = (unsigned int)(c + 0.5f);
    cursor[t] = 0u;
  }
  __syncthreads();
  if (t == 0) {
    unsigned int acc = 0; float ls = 0.f;
    for (int e = 0; e < E_EXP; e++) {
      counts[e] = cn[e];
      offsets[e] = acc;
      acc += cn[e];
      ls += pr[e] * (float)cn[e];
    }
    out_loss[0] = ls * ((float)E_EXP / ((float)S_TOK * (float)S_TOK));
    out_loss[1] = 0.f;
  }
}

// ---------------- listbuild: block-level reservation + inverse map ----------------
__global__ __launch_bounds__(256) void k_listbuild(const TokenRec* __restrict__ te,
                                                   const unsigned int* __restrict__ offsets,
                                                   unsigned int* __restrict__ cursor,
                                                   int* __restrict__ slot_token,
                                                   float* __restrict__ slot_gate,
                                                   int* __restrict__ tok_slot) {
  __shared__ unsigned int lhist[E_EXP];
  __shared__ unsigned int lbase[E_EXP];
  __shared__ unsigned int lcur[E_EXP];
  int t = threadIdx.x, b = blockIdx.x;
  int base = b * 1024;
  if (t < E_EXP) lhist[t] = 0u;
  __syncthreads();
  for (int i = t; i < 1024; i += 256) {
    TokenRec r = te[base + i];
    atomicAdd(&lhist[r.i1], 1u);
    atomicAdd(&lhist[r.i2], 1u);
  }
  __syncthreads();
  if (t < E_EXP) {
    lbase[t] = offsets[t] + atomicAdd(&cursor[t], lhist[t]);
    lcur[t] = 0u;
  }
  __syncthreads();
  for (int i = t; i < 1024; i += 256) {
    int s = base + i;
    TokenRec r = te[s];
    unsigned int p1 = atomicAdd(&lcur[r.i1], 1u);
    int sl1 = (int)(lbase[r.i1] + p1);
    slot_token[sl1] = s; slot_gate[sl1] = r.g1;
    unsigned int p2 = atomicAdd(&lcur[r.i2], 1u);
    int sl2 = (int)(lbase[r.i2] + p2);
    slot_token[sl2] = s; slot_gate[sl2] = r.g2;
    tok_slot[2 * s] = sl1;
    tok_slot[2 * s + 1] = sl2;
  }
}

// ---------------- gather x rows -> fp8 compact activations (k-interleaved) ----------
// within each 64-k block: byte = q*16 + h*8 + j  <->  k = h*32 + q*8 + j
__global__ __launch_bounds__(256) void k_gather(const float* __restrict__ x,
                                                const int* __restrict__ slot_token,
                                                unsigned char* __restrict__ xg) {
  int idx = blockIdx.x * 256 + threadIdx.x;   // 32768 * 64
  int row = idx >> 6, t6 = idx & 63;
  int blk = t6 >> 3, q = (t6 >> 1) & 3, h = t6 & 1;
  int tkn = slot_token[row];
  const float* xp = x + (size_t)tkn * M_DIM + blk * 64 + h * 32 + q * 8;
  f32x4 v0 = *(const f32x4*)xp;
  f32x4 v1 = *(const f32x4*)(xp + 4);
  int b0 = pk8<false>(v0.x, v0.y, 0); b0 = pk8<true>(v0.z, v0.w, b0);
  int b1 = pk8<false>(v1.x, v1.y, 0); b1 = pk8<true>(v1.z, v1.w, b1);
  i32x2 o; o.x = b0; o.y = b1;
  *(i32x2*)&xg[(size_t)row * 512 + blk * 64 + q * 16 + h * 8] = o;
}

// ---------------- weight convert: f32 [E][Kr][Nr] -> fp8 transposed padded,
// k-interleaved [E][Np][Kp]
__global__ __launch_bounds__(256) void k_convw(const float* __restrict__ src,
                                               unsigned char* __restrict__ dst,
                                               int Kr, int Nr, int Kp, int Np) {
  __shared__ float tile[64][65];   // tile[k_local][n_local]
  int e = blockIdx.z;
  int k0 = blockIdx.x * 64, n0 = blockIdx.y * 64;
  int t = threadIdx.x;
  int cx = t & 63, ry = t >> 6;
  const float* sp = src + (size_t)e * Kr * Nr;
#pragma unroll
  for (int i = 0; i < 16; i++) {
    int k = k0 + ry + i * 4, n = n0 + cx;
    float v = (k < Kr && n < Nr) ? sp[(size_t)k * Nr + n] : 0.f;
    tile[ry + i * 4][cx] = v;
  }
  __syncthreads();
  int nl = t >> 2, q = t & 3;
  int b0 = pk8<false>(tile[q * 8 + 0][nl], tile[q * 8 + 1][nl], 0);
  b0 = pk8<true>(tile[q * 8 + 2][nl], tile[q * 8 + 3][nl], b0);
  int b1 = pk8<false>(tile[q * 8 + 4][nl], tile[q * 8 + 5][nl], 0);
  b1 = pk8<true>(tile[q * 8 + 6][nl], tile[q * 8 + 7][nl], b1);
  int c0 = pk8<false>(tile[32 + q * 8 + 0][nl], tile[32 + q * 8 + 1][nl], 0);
  c0 = pk8<true>(tile[32 + q * 8 + 2][nl], tile[32 + q * 8 + 3][nl], c0);
  int c1 = pk8<false>(tile[32 + q * 8 + 4][nl], tile[32 + q * 8 + 5][nl], 0);
  c1 = pk8<true>(tile[32 + q * 8 + 6][nl], tile[32 + q * 8 + 7][nl], c1);
  uint4 pk; pk.x = (unsigned)b0; pk.y = (unsigned)b1; pk.z = (unsigned)c0; pk.w = (unsigned)c1;
  *(uint4*)&dst[(size_t)e * Np * Kp + (size_t)(n0 + nl) * Kp + k0 + q * 16] = pk;
}

// ---------------- grouped GEMM v5 (fp8, BK=64): 128x64 tile, async dbuf staging,
// XOR-swizzled 16-B segments (0 conflicts, same geometry as bf16 v4: row stride 64 B).
// One ds_read_b128 delivers BOTH k-half fragments (interleaved layout).
// mid: out = relu(in @ W^T + b) -> fp8 (pad cols zeroed)
__global__ __launch_bounds__(256, 4) void k_gemm_mid(const unsigned char* __restrict__ in,
                                                  const unsigned char* __restrict__ wt,
                                                  const float* __restrict__ bias,
                                                  unsigned char* __restrict__ out,
                                                  const unsigned int* __restrict__ offsets,
                                                  const unsigned int* __restrict__ counts,
                                                  int KP, int NP, int NREAL) {
  int e = blockIdx.z;
  int n_e = (int)counts[e];
  if (n_e == 0) return;
  int base = (int)offsets[e];
  int bn = blockIdx.y;
  __shared__ __align__(16) unsigned char As[2][128 * 64];  // 2 x 8 KB
  __shared__ __align__(16) unsigned char Bs[2][64 * 64];   // 2 x 4 KB
  int t = threadIdx.x;
  int w = t >> 6, l = t & 63;
  int wm = w & 1, wn = w >> 1;
  int lr = l & 15, lq = l >> 4;
  int r_ = l >> 2, s_ = l & 3;
  int s2 = s_ ^ ((r_ >> 1) & 3);               // swizzled source segment (16 B units)
  int rsw = (lq ^ ((lr >> 1) & 3)) * 16;       // read-side swizzled byte offset
  int c0 = w * 2, c1 = w * 2 + 1;

  unsigned char* dA0[2] = {&As[0][c0 * 1024], &As[1][c0 * 1024]};
  unsigned char* dA1[2] = {&As[0][c1 * 1024], &As[1][c1 * 1024]};
  unsigned char* dB[2]  = {&Bs[0][w * 1024], &Bs[1][w * 1024]};

  const unsigned char* bW = wt + (size_t)e * NP * KP;
  const unsigned char* bsrc = bW + (size_t)(bn * 64 + w * 16 + r_) * KP + s2 * 16;
  int nk = KP >> 6;

  for (int bm = blockIdx.x; bm * 128 < n_e; bm += gridDim.x) {
    int ra = bm * 128 + c0 * 16 + r_; ra = (ra < n_e) ? ra : (n_e - 1);
    int rb = bm * 128 + c1 * 16 + r_; rb = (rb < n_e) ? rb : (n_e - 1);
    const unsigned char* a0 = in + (size_t)(base + ra) * KP + s2 * 16;
    const unsigned char* a1 = in + (size_t)(base + rb) * KP + s2 * 16;
    const unsigned char* bq = bsrc;
    f32x4 acc[4][2];
#pragma unroll
    for (int i = 0; i < 4; i++)
#pragma unroll
      for (int j = 0; j < 2; j++) acc[i][j] = (f32x4){0.f, 0.f, 0.f, 0.f};

    ld_lds16(a0, dA0[0]); ld_lds16(a1, dA1[0]); ld_lds16(bq, dB[0]);
    a0 += 64; a1 += 64; bq += 64;

    for (int ks = 0; ks < nk; ks++) {
      int cb = ks & 1, nb = cb ^ 1;
      __syncthreads();
      if (ks + 1 < nk) {
        ld_lds16(a0, dA0[nb]); ld_lds16(a1, dA1[nb]); ld_lds16(bq, dB[nb]);
        a0 += 64; a1 += 64; bq += 64;
      }
      lx2 af[4], bf[2];
#pragma unroll
      for (int mt = 0; mt < 4; mt++) af[mt] = *(const lx2*)&As[cb][(wm * 64 + mt * 16 + lr) * 64 + rsw];
#pragma unroll
      for (int nt = 0; nt < 2; nt++) bf[nt] = *(const lx2*)&Bs[cb][(wn * 32 + nt * 16 + lr) * 64 + rsw];
#pragma unroll
      for (int mt = 0; mt < 4; mt++)
#pragma unroll
        for (int nt = 0; nt < 2; nt++) {
          acc[mt][nt] = __builtin_amdgcn_mfma_f32_16x16x32_fp8_fp8(af[mt].x, bf[nt].x, acc[mt][nt], 0, 0, 0);
          acc[mt][nt] = __builtin_amdgcn_mfma_f32_16x16x32_fp8_fp8(af[mt].y, bf[nt].y, acc[mt][nt], 0, 0, 0);
        }
    }

#pragma unroll
    for (int nt = 0; nt < 2; nt++) {
      int col = bn * 64 + wn * 32 + nt * 16 + lr;
      bool cok = col < NREAL;
      float bv = cok ? bias[(size_t)e * NREAL + col] : 0.f;
      int kl = col & 63;
      int pb = ((kl >> 3) & 3) * 16 + ((kl >> 5) & 1) * 8 + (kl & 7);
#pragma unroll
      for (int mt = 0; mt < 4; mt++)
#pragma unroll
        for (int reg = 0; reg < 4; reg++) {
          int r = bm * 128 + wm * 64 + mt * 16 + lq * 4 + reg;
          if (r < n_e) {
            float v = cok ? fmaxf(acc[mt][nt][reg] + bv, 0.f) : 0.f;
            out[(size_t)(base + r) * NP + bn * 64 + pb] = f2fp8(v);
          }
        }
    }
  }
}

// fin: eo[slot] = gate * (h3 @ W4 + b4); plain coalesced f32 stores
__global__ __launch_bounds__(256, 4) void k_gemm_fin(const unsigned char* __restrict__ in,
                                                  const unsigned char* __restrict__ wt,
                                                  const float* __restrict__ bias,
                                                  float* __restrict__ eo,
                                                  const unsigned int* __restrict__ offsets,
                                                  const unsigned int* __restrict__ counts,
                                                  const float* __restrict__ slot_gate) {
  const int KP = 1024, NP = 256;
  int e = blockIdx.z;
  int n_e = (int)counts[e];
  if (n_e == 0) return;
  int base = (int)offsets[e];
  int bn = blockIdx.y;
  __shared__ __align__(16) unsigned char As[2][128 * 64];
  __shared__ __align__(16) unsigned char Bs[2][64 * 64];
  int t = threadIdx.x;
  int w = t >> 6, l = t & 63;
  int wm = w & 1, wn = w >> 1;
  int lr = l & 15, lq = l >> 4;
  int r_ = l >> 2, s_ = l & 3;
  int s2 = s_ ^ ((r_ >> 1) & 3);
  int rsw = (lq ^ ((lr >> 1) & 3)) * 16;
  int c0 = w * 2, c1 = w * 2 + 1;

  unsigned char* dA0[2] = {&As[0][c0 * 1024], &As[1][c0 * 1024]};
  unsigned char* dA1[2] = {&As[0][c1 * 1024], &As[1][c1 * 1024]};
  unsigned char* dB[2]  = {&Bs[0][w * 1024], &Bs[1][w * 1024]};

  const unsigned char* bW = wt + (size_t)e * NP * KP;
  const unsigned char* bsrc = bW + (size_t)(bn * 64 + w * 16 + r_) * KP + s2 * 16;
  int nk = KP >> 6;

  for (int bm = blockIdx.x; bm * 128 < n_e; bm += gridDim.x) {
    int ra = bm * 128 + c0 * 16 + r_; ra = (ra < n_e) ? ra : (n_e - 1);
    int rb = bm * 128 + c1 * 16 + r_; rb = (rb < n_e) ? rb : (n_e - 1);
    const unsigned char* a0 = in + (size_t)(base + ra) * KP + s2 * 16;
    const unsigned char* a1 = in + (size_t)(base + rb) * KP + s2 * 16;
    const unsigned char* bq = bsrc;
    f32x4 acc[4][2];
#pragma unroll
    for (int i = 0; i < 4; i++)
#pragma unroll
      for (int j = 0; j < 2; j++) acc[i][j] = (f32x4){0.f, 0.f, 0.f, 0.f};

    ld_lds16(a0, dA0[0]); ld_lds16(a1, dA1[0]); ld_lds16(bq, dB[0]);
    a0 += 64; a1 += 64; bq += 64;

    for (int ks = 0; ks < nk; ks++) {
      int cb = ks & 1, nb = cb ^ 1;
      __syncthreads();
      if (ks + 1 < nk) {
        ld_lds16(a0, dA0[nb]); ld_lds16(a1, dA1[nb]); ld_lds16(bq, dB[nb]);
        a0 += 64; a1 += 64; bq += 64;
      }
      lx2 af[4], bf[2];
#pragma unroll
      for (int mt = 0; mt < 4; mt++) af[mt] = *(const lx2*)&As[cb][(wm * 64 + mt * 16 + lr) * 64 + rsw];
#pragma unroll
      for (int nt = 0; nt < 2; nt++) bf[nt] = *(const lx2*)&Bs[cb][(wn * 32 + nt * 16 + lr) * 64 + rsw];
#pragma unroll
      for (int mt = 0; mt < 4; mt++)
#pragma unroll
        for (int nt = 0; nt < 2; nt++) {
          acc[mt][nt] = __builtin_amdgcn_mfma_f32_16x16x32_fp8_fp8(af[mt].x, bf[nt].x, acc[mt][nt], 0, 0, 0);
          acc[mt][nt] = __builtin_amdgcn_mfma_f32_16x16x32_fp8_fp8(af[mt].y, bf[nt].y, acc[mt][nt], 0, 0, 0);
        }
    }

#pragma unroll
    for (int mt = 0; mt < 4; mt++)
#pragma unroll
      for (int reg = 0; reg < 4; reg++) {
        int r = bm * 128 + wm * 64 + mt * 16 + lq * 4 + reg;
        if (r < n_e) {
          int gr = base + r;
          float g = slot_gate[gr];
#pragma unroll
          for (int nt = 0; nt < 2; nt++) {
            int col = bn * 64 + wn * 32 + nt * 16 + lr;
            eo[(size_t)gr * NP + col] = g * (acc[mt][nt][reg] + bias[(size_t)e * 256 + col]);
          }
        }
      }
  }
}

// ---------------- combine: out[s] = eo[sl1(s)] + eo[sl2(s)] ----------------
__global__ __launch_bounds__(256) void k_combine(const float* __restrict__ eo,
                                                 const int* __restrict__ tok_slot,
                                                 float* __restrict__ out) {
  int idx = blockIdx.x * 256 + threadIdx.x;
  int s = idx >> 6, q = idx & 63;
  int sl1 = tok_slot[2 * s], sl2 = tok_slot[2 * s + 1];
  f32x4 v1 = *(const f32x4*)&eo[(size_t)sl1 * D_OUT + q * 4];
  f32x4 v2 = *(const f32x4*)&eo[(size_t)sl2 * D_OUT + q * 4];
  *(f32x4*)&out[(size_t)s * D_OUT + q * 4] = v1 + v2;
}

extern "C" void kernel_launch(void* const* d_in, const int* in_sizes, int n_in,
                              void* d_out, int out_size, void* d_ws, size_t ws_size,
                              hipStream_t stream) {
  const float* x    = (const float*)d_in[0];
  const float* nois = (const float*)d_in[1];
  const float* Wr   = (const float*)d_in[2];
  const float* W1   = (const float*)d_in[3];
  const float* b1   = (const float*)d_in[4];
  const float* W2   = (const float*)d_in[5];
  const float* b2   = (const float*)d_in[6];
  const float* W3   = (const float*)d_in[7];
  const float* b3   = (const float*)d_in[8];
  const float* W4   = (const float*)d_in[9];
  const float* b4   = (const float*)d_in[10];
  float* out = (float*)d_out;

  char* w = (char*)d_ws;
  unsigned char* actA = (unsigned char*)(w + 0);          // 32768*1024 fp8 = 33554432 B
  unsigned char* actB = (unsigned char*)(w + 33554432);   // 32768*512 fp8  = 16777216 B
  unsigned char* Wt   = (unsigned char*)(w + 50331648);   // <=16*1024*512 fp8 = 8388608 B
  float*         eo   = (float*)(w + 58720256);           // 32768*256 f32 = 33554432 B
  int*           slot_token = (int*)(w + 92274688);       // 131072 B
  float*         slot_gate  = (float*)(w + 92405760);     // 131072 B
  TokenRec*      te         = (TokenRec*)(w + 92536832);  // 262144 B
  unsigned int*  counts  = (unsigned int*)(w + 92798976);
  unsigned int*  cursor  = (unsigned int*)(w + 92799040);
  unsigned int*  offsets = (unsigned int*)(w + 92799104);
  int*           tok_slot = (int*)(w + 92799232);         // 131072 B
  // transient overlays on actA (dead before L1 GEMM writes actA)
  float*         sel_buf  = (float*)(w + 0);              // 1 MB
  float*         partials = (float*)(w + 1048576);        // 2 KB

  float* sel_out  = out + (size_t)S_TOK * D_OUT;
  float* loss_out = out + (size_t)S_TOK * D_OUT + (size_t)S_TOK * E_EXP;

  k_router<<<dim3(S_TOK / 16), dim3(256), 0, stream>>>(x, nois, Wr, sel_out, sel_buf, te);
  k_stats<<<dim3(16), dim3(256), 0, stream>>>(sel_buf, te, partials);
  k_prefix_loss<<<dim3(1), dim3(64), 0, stream>>>(partials, counts, offsets, cursor, loss_out);
  k_listbuild<<<dim3(16), dim3(256), 0, stream>>>(te, offsets, cursor, slot_token, slot_gate, tok_slot);
  k_gather<<<dim3((2 * S_TOK * 64) / 256), dim3(256), 0, stream>>>(x, slot_token, actB);

  // Layer 1: [*,512] @ [512,500] -> relu -> actA (stride 512)
  k_convw<<<dim3(8, 8, E_EXP), dim3(256), 0, stream>>>(W1, Wt, 512, H1D, 512, 512);
  k_gemm_mid<<<dim3(24, 8, E_EXP), dim3(256), 0, stream>>>(actB, Wt, b1, actA, offsets, counts, 512, 512, H1D);
  // Layer 2: [*,500] @ [500,500] -> relu -> actB (stride 512)
  k_convw<<<dim3(8, 8, E_EXP), dim3(256), 0, stream>>>(W2, Wt, H1D, H2D, 512, 512);
  k_gemm_mid<<<dim3(24, 8, E_EXP), dim3(256), 0, stream>>>(actA, Wt, b2, actB, offsets, counts, 512, 512, H2D);
  // Layer 3: [*,500] @ [500,1000] -> relu -> actA (stride 1024)
  k_convw<<<dim3(8, 16, E_EXP), dim3(256), 0, stream>>>(W3, Wt, H2D, H3D, 512, 1024);
  k_gemm_mid<<<dim3(24, 16, E_EXP), dim3(256), 0, stream>>>(actB, Wt, b3, actA, offsets, counts, 512, 1024, H3D);
  // Layer 4: [*,1000] @ [1000,256] -> eo[slot] = gate*(h3@W4+b4)
  k_convw<<<dim3(16, 4, E_EXP), dim3(256), 0, stream>>>(W4, Wt, H3D, D_OUT, 1024, 256);
  k_gemm_fin<<<dim3(24, 4, E_EXP), dim3(256), 0, stream>>>(actA, Wt, b4, eo, offsets, counts, slot_gate);
  // Combine: out[s] = eo[sl1] + eo[sl2]
  k_combine<<<dim3(S_TOK * 64 / 256), dim3(256), 0, stream>>>(eo, tok_slot, out);

  (void)in_sizes; (void)n_in; (void)out_size; (void)ws_size;
}

// Round 9
// 379.025 us; speedup vs baseline: 1.6763x; 1.0176x over previous
//
#include <hip/hip_runtime.h>
#include <stdint.h>

#define S_TOK 16384
#define M_DIM 512
#define E_EXP 16
#define D_OUT 256
#define H1D 500
#define H2D 500
#define H3D 1000

typedef float f32x4 __attribute__((ext_vector_type(4)));
typedef long lx2 __attribute__((ext_vector_type(2)));   // 16 B = two fp8 fragments
typedef int i32x2 __attribute__((ext_vector_type(2)));

template <bool HI>
__device__ __forceinline__ int pk8(float a, float b, int old) {
  return __builtin_amdgcn_cvt_pk_fp8_f32(a, b, old, HI);
}
__device__ __forceinline__ unsigned char f2fp8(float f) {
  return (unsigned char)(__builtin_amdgcn_cvt_pk_fp8_f32(f, 0.f, 0, false) & 0xff);
}

// async global->LDS, 16B per lane; LDS dest = wave-uniform base + lane*16
__device__ __forceinline__ void ld_lds16(const unsigned char* g, unsigned char* l) {
  __builtin_amdgcn_global_load_lds(
      (const __attribute__((address_space(1))) unsigned int*)(const void*)g,
      (__attribute__((address_space(3))) unsigned int*)(void*)l, 16, 0, 0);
}

struct TokenRec { int i1, i2; float g1, g2; };

// ---------------- router: lane-parallel experts, f64 accum, no global atomics ------
__global__ __launch_bounds__(256) void k_router(const float* __restrict__ x,
                                                const float* __restrict__ noise,
                                                const float* __restrict__ Wr,
                                                float* __restrict__ sel_out,
                                                float* __restrict__ sel_buf,
                                                TokenRec* __restrict__ te) {
  __shared__ float wr[E_EXP * 516];   // pad 516: 2-way LDS aliasing only (free)
  int t = threadIdx.x;
  for (int i = t; i < E_EXP * M_DIM; i += 256) {
    int e = i >> 9, m = i & 511;
    wr[e * 516 + m] = Wr[i];
  }
  __syncthreads();

  int wv = t >> 6, l = t & 63;
  int e = l & 15, tg = l >> 4;
  int s = blockIdx.x * 16 + wv * 4 + tg;

  const float* xr = x + (size_t)s * M_DIM;
  const float* wre = &wr[e * 516];
  double a0 = 0.0, a1 = 0.0, a2 = 0.0, a3 = 0.0;
#pragma unroll 4
  for (int m = 0; m < M_DIM; m += 4) {
    f32x4 xv = *(const f32x4*)(xr + m);
    f32x4 wv4 = *(const f32x4*)(wre + m);
    a0 += (double)xv.x * (double)wv4.x;
    a1 += (double)xv.y * (double)wv4.y;
    a2 += (double)xv.z * (double)wv4.z;
    a3 += (double)xv.w * (double)wv4.w;
  }
  double a = (a0 + a1) + (a2 + a3);
  a += (double)noise[(size_t)s * E_EXP + e];

  double mx = a;
#pragma unroll
  for (int off = 8; off >= 1; off >>= 1) { double o = __shfl_xor(mx, off, 64); mx = (o > mx) ? o : mx; }
  double p = exp(a - mx);
  double sum = p;
#pragma unroll
  for (int off = 8; off >= 1; off >>= 1) sum += __shfl_xor(sum, off, 64);
  sel_buf[(size_t)s * E_EXP + e] = (float)(p / sum);

  unsigned long long pb = __double_as_longlong(p);
  unsigned long long key = (pb & ~0xFFull) | (unsigned long long)(255 - e);
  unsigned long long k1 = key;
#pragma unroll
  for (int off = 8; off >= 1; off >>= 1) { unsigned long long o = __shfl_xor(k1, off, 64); k1 = (o > k1) ? o : k1; }
  int i1 = 255 - (int)(k1 & 0xFFull);
  unsigned long long key2 = (e == i1) ? 0ull : key;
  unsigned long long k2 = key2;
#pragma unroll
  for (int off = 8; off >= 1; off >>= 1) { unsigned long long o = __shfl_xor(k2, off, 64); k2 = (o > k2) ? o : k2; }
  int i2 = 255 - (int)(k2 & 0xFFull);

  double p1 = __shfl(p, tg * 16 + i1, 64);
  double p2 = __shfl(p, tg * 16 + i2, 64);

  sel_out[(size_t)s * E_EXP + e] = (e == i1 || e == i2) ? 1.f : 0.f;
  if (e == 0) {
    double inv = 1.0 / (p1 + p2);
    TokenRec r; r.i1 = i1; r.i2 = i2; r.g1 = (float)(p1 * inv); r.g2 = (float)(p2 * inv);
    te[s] = r;
  }
}

// ---------------- stats: per-block proxy partial sums + histogram ----------------
__global__ __launch_bounds__(256) void k_stats(const float* __restrict__ sel_buf,
                                               const TokenRec* __restrict__ te,
                                               float* __restrict__ partials) {  // [16][32]
  __shared__ float psum[256];
  __shared__ unsigned int hist[E_EXP];
  int t = threadIdx.x, b = blockIdx.x;
  if (t < E_EXP) hist[t] = 0u;
  __syncthreads();
  int e = t & 15, rg = t >> 4;
  int base = b * 1024;
  float acc = 0.f;
#pragma unroll 4
  for (int i = 0; i < 64; i++)
    acc += sel_buf[(size_t)(base + i * 16 + rg) * E_EXP + e];
  for (int i = t; i < 1024; i += 256) {
    TokenRec r = te[base + i];
    atomicAdd(&hist[r.i1], 1u);
    atomicAdd(&hist[r.i2], 1u);
  }
  psum[t] = acc;
  __syncthreads();
  if (t < E_EXP) {
    float v = 0.f;
#pragma unroll
    for (int rg2 = 0; rg2 < 16; rg2++) v += psum[rg2 * 16 + t];
    partials[b * 32 + t] = v;
    partials[b * 32 + 16 + t] = (float)hist[t];
  }
}

// ---------------- reduce partials -> counts/offsets + balance loss + cursor init ------
__global__ void k_prefix_loss(const float* __restrict__ partials,
                              unsigned int* __restrict__ counts,
                              unsigned int* __restrict__ offsets,
                              unsigned int* __restrict__ cursor,
                              float* __restrict__ out_loss) {
  __shared__ float pr[E_EXP];
  __shared__ unsigned int cn[E_EXP];
  int t = threadIdx.x;
  if (t < E_EXP) {
    float p = 0.f, c = 0.f;
    for (int b = 0; b < 16; b++) { p += partials[b * 32 + t]; c += partials[b * 32 + 16 + t]; }
    pr[t] = p; cn[t] = (unsigned int)(c + 0.5f);
    cursor[t] = 0u;
  }
  __syncthreads();
  if (t == 0) {
    unsigned int acc = 0; float ls = 0.f;
    for (int e = 0; e < E_EXP; e++) {
      counts[e] = cn[e];
      offsets[e] = acc;
      acc += cn[e];
      ls += pr[e] * (float)cn[e];
    }
    out_loss[0] = ls * ((float)E_EXP / ((float)S_TOK * (float)S_TOK));
    out_loss[1] = 0.f;
  }
}

// ---------------- listbuild: block-level reservation + inverse map ----------------
__global__ __launch_bounds__(256) void k_listbuild(const TokenRec* __restrict__ te,
                                                   const unsigned int* __restrict__ offsets,
                                                   unsigned int* __restrict__ cursor,
                                                   int* __restrict__ slot_token,
                                                   float* __restrict__ slot_gate,
                                                   int* __restrict__ tok_slot) {
  __shared__ unsigned int lhist[E_EXP];
  __shared__ unsigned int lbase[E_EXP];
  __shared__ unsigned int lcur[E_EXP];
  int t = threadIdx.x, b = blockIdx.x;
  int base = b * 1024;
  if (t < E_EXP) lhist[t] = 0u;
  __syncthreads();
  for (int i = t; i < 1024; i += 256) {
    TokenRec r = te[base + i];
    atomicAdd(&lhist[r.i1], 1u);
    atomicAdd(&lhist[r.i2], 1u);
  }
  __syncthreads();
  if (t < E_EXP) {
    lbase[t] = offsets[t] + atomicAdd(&cursor[t], lhist[t]);
    lcur[t] = 0u;
  }
  __syncthreads();
  for (int i = t; i < 1024; i += 256) {
    int s = base + i;
    TokenRec r = te[s];
    unsigned int p1 = atomicAdd(&lcur[r.i1], 1u);
    int sl1 = (int)(lbase[r.i1] + p1);
    slot_token[sl1] = s; slot_gate[sl1] = r.g1;
    unsigned int p2 = atomicAdd(&lcur[r.i2], 1u);
    int sl2 = (int)(lbase[r.i2] + p2);
    slot_token[sl2] = s; slot_gate[sl2] = r.g2;
    tok_slot[2 * s] = sl1;
    tok_slot[2 * s + 1] = sl2;
  }
}

// ---------------- gather x rows -> fp8 compact activations (k-interleaved) ----------
// within each 64-k block: byte = q*16 + h*8 + j  <->  k = h*32 + q*8 + j
__global__ __launch_bounds__(256) void k_gather(const float* __restrict__ x,
                                                const int* __restrict__ slot_token,
                                                unsigned char* __restrict__ xg) {
  int idx = blockIdx.x * 256 + threadIdx.x;   // 32768 * 64
  int row = idx >> 6, t6 = idx & 63;
  int blk = t6 >> 3, q = (t6 >> 1) & 3, h = t6 & 1;
  int tkn = slot_token[row];
  const float* xp = x + (size_t)tkn * M_DIM + blk * 64 + h * 32 + q * 8;
  f32x4 v0 = *(const f32x4*)xp;
  f32x4 v1 = *(const f32x4*)(xp + 4);
  int b0 = pk8<false>(v0.x, v0.y, 0); b0 = pk8<true>(v0.z, v0.w, b0);
  int b1 = pk8<false>(v1.x, v1.y, 0); b1 = pk8<true>(v1.z, v1.w, b1);
  i32x2 o; o.x = b0; o.y = b1;
  *(i32x2*)&xg[(size_t)row * 512 + blk * 64 + q * 16 + h * 8] = o;
}

// ---------------- fused weight convert (all 4 layers, one launch) --------------------
// f32 [E][Kr][Nr] -> fp8 transposed padded, k-interleaved [E][Np][Kp]
__global__ __launch_bounds__(256) void k_convw_all(const float* __restrict__ W1,
                                                   const float* __restrict__ W2,
                                                   const float* __restrict__ W3,
                                                   const float* __restrict__ W4,
                                                   unsigned char* __restrict__ D1,
                                                   unsigned char* __restrict__ D2,
                                                   unsigned char* __restrict__ D3,
                                                   unsigned char* __restrict__ D4) {
  __shared__ float tile[64][65];   // tile[k_local][n_local]
  int tb = blockIdx.x, e = blockIdx.y;
  const float* src; unsigned char* dst;
  int Kr, Nr, Kp, Np, kx, ny;
  if (tb < 64)        { src = W1; dst = D1; Kr = 512;  Nr = H1D; Kp = 512;  Np = 512;  kx = tb >> 3;  ny = tb & 7; }
  else if (tb < 128)  { tb -= 64;  src = W2; dst = D2; Kr = H1D; Nr = H2D; Kp = 512;  Np = 512;  kx = tb >> 3;  ny = tb & 7; }
  else if (tb < 256)  { tb -= 128; src = W3; dst = D3; Kr = H2D; Nr = H3D; Kp = 512;  Np = 1024; kx = tb >> 4;  ny = tb & 15; }
  else                { tb -= 256; src = W4; dst = D4; Kr = H3D; Nr = 256; Kp = 1024; Np = 256;  kx = tb >> 2;  ny = tb & 3; }
  int k0 = kx * 64, n0 = ny * 64;
  int t = threadIdx.x;
  int cx = t & 63, ry = t >> 6;
  const float* sp = src + (size_t)e * Kr * Nr;
#pragma unroll
  for (int i = 0; i < 16; i++) {
    int k = k0 + ry + i * 4, n = n0 + cx;
    float v = (k < Kr && n < Nr) ? sp[(size_t)k * Nr + n] : 0.f;
    tile[ry + i * 4][cx] = v;
  }
  __syncthreads();
  int nl = t >> 2, q = t & 3;
  int b0 = pk8<false>(tile[q * 8 + 0][nl], tile[q * 8 + 1][nl], 0);
  b0 = pk8<true>(tile[q * 8 + 2][nl], tile[q * 8 + 3][nl], b0);
  int b1 = pk8<false>(tile[q * 8 + 4][nl], tile[q * 8 + 5][nl], 0);
  b1 = pk8<true>(tile[q * 8 + 6][nl], tile[q * 8 + 7][nl], b1);
  int c0 = pk8<false>(tile[32 + q * 8 + 0][nl], tile[32 + q * 8 + 1][nl], 0);
  c0 = pk8<true>(tile[32 + q * 8 + 2][nl], tile[32 + q * 8 + 3][nl], c0);
  int c1 = pk8<false>(tile[32 + q * 8 + 4][nl], tile[32 + q * 8 + 5][nl], 0);
  c1 = pk8<true>(tile[32 + q * 8 + 6][nl], tile[32 + q * 8 + 7][nl], c1);
  uint4 pk; pk.x = (unsigned)b0; pk.y = (unsigned)b1; pk.z = (unsigned)c0; pk.w = (unsigned)c1;
  *(uint4*)&dst[(size_t)e * Np * Kp + (size_t)(n0 + nl) * Kp + k0 + q * 16] = pk;
}

// ---------------- grouped GEMM (fp8, BK=64): 128x64 tile, async dbuf staging,
// XOR-swizzled 16-B segments (0 conflicts). One ds_read_b128 = both k-half frags.
// mid: out = relu(in @ W^T + b) -> fp8 (pad cols zeroed)
__global__ __launch_bounds__(256, 4) void k_gemm_mid(const unsigned char* __restrict__ in,
                                                  const unsigned char* __restrict__ wt,
                                                  const float* __restrict__ bias,
                                                  unsigned char* __restrict__ out,
                                                  const unsigned int* __restrict__ offsets,
                                                  const unsigned int* __restrict__ counts,
                                                  int KP, int NP, int NREAL) {
  int e = blockIdx.z;
  int n_e = (int)counts[e];
  if (n_e == 0) return;
  int base = (int)offsets[e];
  int bn = blockIdx.y;
  __shared__ __align__(16) unsigned char As[2][128 * 64];  // 2 x 8 KB
  __shared__ __align__(16) unsigned char Bs[2][64 * 64];   // 2 x 4 KB
  int t = threadIdx.x;
  int w = t >> 6, l = t & 63;
  int wm = w & 1, wn = w >> 1;
  int lr = l & 15, lq = l >> 4;
  int r_ = l >> 2, s_ = l & 3;
  int s2 = s_ ^ ((r_ >> 1) & 3);               // swizzled source segment (16 B units)
  int rsw = (lq ^ ((lr >> 1) & 3)) * 16;       // read-side swizzled byte offset
  int c0 = w * 2, c1 = w * 2 + 1;

  unsigned char* dA0[2] = {&As[0][c0 * 1024], &As[1][c0 * 1024]};
  unsigned char* dA1[2] = {&As[0][c1 * 1024], &As[1][c1 * 1024]};
  unsigned char* dB[2]  = {&Bs[0][w * 1024], &Bs[1][w * 1024]};

  const unsigned char* bW = wt + (size_t)e * NP * KP;
  const unsigned char* bsrc = bW + (size_t)(bn * 64 + w * 16 + r_) * KP + s2 * 16;
  int nk = KP >> 6;

  for (int bm = blockIdx.x; bm * 128 < n_e; bm += gridDim.x) {
    int ra = bm * 128 + c0 * 16 + r_; ra = (ra < n_e) ? ra : (n_e - 1);
    int rb = bm * 128 + c1 * 16 + r_; rb = (rb < n_e) ? rb : (n_e - 1);
    const unsigned char* a0 = in + (size_t)(base + ra) * KP + s2 * 16;
    const unsigned char* a1 = in + (size_t)(base + rb) * KP + s2 * 16;
    const unsigned char* bq = bsrc;
    f32x4 acc[4][2];
#pragma unroll
    for (int i = 0; i < 4; i++)
#pragma unroll
      for (int j = 0; j < 2; j++) acc[i][j] = (f32x4){0.f, 0.f, 0.f, 0.f};

    ld_lds16(a0, dA0[0]); ld_lds16(a1, dA1[0]); ld_lds16(bq, dB[0]);
    a0 += 64; a1 += 64; bq += 64;

    for (int ks = 0; ks < nk; ks++) {
      int cb = ks & 1, nb = cb ^ 1;
      __syncthreads();
      if (ks + 1 < nk) {
        ld_lds16(a0, dA0[nb]); ld_lds16(a1, dA1[nb]); ld_lds16(bq, dB[nb]);
        a0 += 64; a1 += 64; bq += 64;
      }
      lx2 af[4], bf[2];
#pragma unroll
      for (int mt = 0; mt < 4; mt++) af[mt] = *(const lx2*)&As[cb][(wm * 64 + mt * 16 + lr) * 64 + rsw];
#pragma unroll
      for (int nt = 0; nt < 2; nt++) bf[nt] = *(const lx2*)&Bs[cb][(wn * 32 + nt * 16 + lr) * 64 + rsw];
#pragma unroll
      for (int mt = 0; mt < 4; mt++)
#pragma unroll
        for (int nt = 0; nt < 2; nt++) {
          acc[mt][nt] = __builtin_amdgcn_mfma_f32_16x16x32_fp8_fp8(af[mt].x, bf[nt].x, acc[mt][nt], 0, 0, 0);
          acc[mt][nt] = __builtin_amdgcn_mfma_f32_16x16x32_fp8_fp8(af[mt].y, bf[nt].y, acc[mt][nt], 0, 0, 0);
        }
    }

#pragma unroll
    for (int nt = 0; nt < 2; nt++) {
      int col = bn * 64 + wn * 32 + nt * 16 + lr;
      bool cok = col < NREAL;
      float bv = cok ? bias[(size_t)e * NREAL + col] : 0.f;
      int kl = col & 63;
      int pb = ((kl >> 3) & 3) * 16 + ((kl >> 5) & 1) * 8 + (kl & 7);
#pragma unroll
      for (int mt = 0; mt < 4; mt++)
#pragma unroll
        for (int reg = 0; reg < 4; reg++) {
          int r = bm * 128 + wm * 64 + mt * 16 + lq * 4 + reg;
          if (r < n_e) {
            float v = cok ? fmaxf(acc[mt][nt][reg] + bv, 0.f) : 0.f;
            out[(size_t)(base + r) * NP + bn * 64 + pb] = f2fp8(v);
          }
        }
    }
  }
}

// fin: 64x64 tile (2x2 waves of 32x32) for 2x block parallelism on K=1024.
// eo[slot] = gate * (h3 @ W4 + b4); plain coalesced f32 stores
__global__ __launch_bounds__(256, 4) void k_gemm_fin(const unsigned char* __restrict__ in,
                                                  const unsigned char* __restrict__ wt,
                                                  const float* __restrict__ bias,
                                                  float* __restrict__ eo,
                                                  const unsigned int* __restrict__ offsets,
                                                  const unsigned int* __restrict__ counts,
                                                  const float* __restrict__ slot_gate) {
  const int KP = 1024, NP = 256;
  int e = blockIdx.z;
  int n_e = (int)counts[e];
  if (n_e == 0) return;
  int base = (int)offsets[e];
  int bn = blockIdx.y;
  __shared__ __align__(16) unsigned char As[2][64 * 64];   // 2 x 4 KB
  __shared__ __align__(16) unsigned char Bs[2][64 * 64];   // 2 x 4 KB
  int t = threadIdx.x;
  int w = t >> 6, l = t & 63;
  int wm = w & 1, wn = w >> 1;
  int lr = l & 15, lq = l >> 4;
  int r_ = l >> 2, s_ = l & 3;
  int s2 = s_ ^ ((r_ >> 1) & 3);
  int rsw = (lq ^ ((lr >> 1) & 3)) * 16;

  unsigned char* dA[2] = {&As[0][w * 1024], &As[1][w * 1024]};   // wave w stages rows w*16..+15
  unsigned char* dB[2] = {&Bs[0][w * 1024], &Bs[1][w * 1024]};

  const unsigned char* bW = wt + (size_t)e * NP * KP;
  const unsigned char* bsrc = bW + (size_t)(bn * 64 + w * 16 + r_) * KP + s2 * 16;
  int nk = KP >> 6;

  for (int bm = blockIdx.x; bm * 64 < n_e; bm += gridDim.x) {
    int ra = bm * 64 + w * 16 + r_; ra = (ra < n_e) ? ra : (n_e - 1);
    const unsigned char* a0 = in + (size_t)(base + ra) * KP + s2 * 16;
    const unsigned char* bq = bsrc;
    f32x4 acc[2][2];
#pragma unroll
    for (int i = 0; i < 2; i++)
#pragma unroll
      for (int j = 0; j < 2; j++) acc[i][j] = (f32x4){0.f, 0.f, 0.f, 0.f};

    ld_lds16(a0, dA[0]); ld_lds16(bq, dB[0]);
    a0 += 64; bq += 64;

    for (int ks = 0; ks < nk; ks++) {
      int cb = ks & 1, nb = cb ^ 1;
      __syncthreads();
      if (ks + 1 < nk) {
        ld_lds16(a0, dA[nb]); ld_lds16(bq, dB[nb]);
        a0 += 64; bq += 64;
      }
      lx2 af[2], bf[2];
#pragma unroll
      for (int mt = 0; mt < 2; mt++) af[mt] = *(const lx2*)&As[cb][(wm * 32 + mt * 16 + lr) * 64 + rsw];
#pragma unroll
      for (int nt = 0; nt < 2; nt++) bf[nt] = *(const lx2*)&Bs[cb][(wn * 32 + nt * 16 + lr) * 64 + rsw];
#pragma unroll
      for (int mt = 0; mt < 2; mt++)
#pragma unroll
        for (int nt = 0; nt < 2; nt++) {
          acc[mt][nt] = __builtin_amdgcn_mfma_f32_16x16x32_fp8_fp8(af[mt].x, bf[nt].x, acc[mt][nt], 0, 0, 0);
          acc[mt][nt] = __builtin_amdgcn_mfma_f32_16x16x32_fp8_fp8(af[mt].y, bf[nt].y, acc[mt][nt], 0, 0, 0);
        }
    }

#pragma unroll
    for (int mt = 0; mt < 2; mt++)
#pragma unroll
      for (int reg = 0; reg < 4; reg++) {
        int r = bm * 64 + wm * 32 + mt * 16 + lq * 4 + reg;
        if (r < n_e) {
          int gr = base + r;
          float g = slot_gate[gr];
#pragma unroll
          for (int nt = 0; nt < 2; nt++) {
            int col = bn * 64 + wn * 32 + nt * 16 + lr;
            eo[(size_t)gr * NP + col] = g * (acc[mt][nt][reg] + bias[(size_t)e * 256 + col]);
          }
        }
      }
  }
}

// ---------------- combine: out[s] = eo[sl1(s)] + eo[sl2(s)] ----------------
__global__ __launch_bounds__(256) void k_combine(const float* __restrict__ eo,
                                                 const int* __restrict__ tok_slot,
                                                 float* __restrict__ out) {
  int idx = blockIdx.x * 256 + threadIdx.x;
  int s = idx >> 6, q = idx & 63;
  int sl1 = tok_slot[2 * s], sl2 = tok_slot[2 * s + 1];
  f32x4 v1 = *(const f32x4*)&eo[(size_t)sl1 * D_OUT + q * 4];
  f32x4 v2 = *(const f32x4*)&eo[(size_t)sl2 * D_OUT + q * 4];
  *(f32x4*)&out[(size_t)s * D_OUT + q * 4] = v1 + v2;
}

extern "C" void kernel_launch(void* const* d_in, const int* in_sizes, int n_in,
                              void* d_out, int out_size, void* d_ws, size_t ws_size,
                              hipStream_t stream) {
  const float* x    = (const float*)d_in[0];
  const float* nois = (const float*)d_in[1];
  const float* Wr   = (const float*)d_in[2];
  const float* W1   = (const float*)d_in[3];
  const float* b1   = (const float*)d_in[4];
  const float* W2   = (const float*)d_in[5];
  const float* b2   = (const float*)d_in[6];
  const float* W3   = (const float*)d_in[7];
  const float* b3   = (const float*)d_in[8];
  const float* W4   = (const float*)d_in[9];
  const float* b4   = (const float*)d_in[10];
  float* out = (float*)d_out;

  char* w = (char*)d_ws;
  unsigned char* actA = (unsigned char*)(w + 0);          // 32768*1024 fp8 = 33554432 B
  unsigned char* actB = (unsigned char*)(w + 33554432);   // 32768*512 fp8  = 16777216 B
  unsigned char* Wt1  = (unsigned char*)(w + 50331648);   // 16*512*512   = 4 MB
  unsigned char* Wt2  = (unsigned char*)(w + 54525952);   // 4 MB
  unsigned char* Wt3  = (unsigned char*)(w + 58720256);   // 16*1024*512  = 8 MB
  unsigned char* Wt4  = (unsigned char*)(w + 67108864);   // 16*256*1024  = 4 MB
  float*         eo   = (float*)(w + 71303168);           // 32768*256 f32 = 33554432 B
  int*           slot_token = (int*)(w + 104857600);      // 131072 B
  float*         slot_gate  = (float*)(w + 104988672);    // 131072 B
  TokenRec*      te         = (TokenRec*)(w + 105119744); // 262144 B
  unsigned int*  counts  = (unsigned int*)(w + 105381888);
  unsigned int*  cursor  = (unsigned int*)(w + 105381952);
  unsigned int*  offsets = (unsigned int*)(w + 105382016);
  int*           tok_slot = (int*)(w + 105382080);        // 131072 B
  // transient overlays on actA (dead before L1 GEMM writes actA)
  float*         sel_buf  = (float*)(w + 0);              // 1 MB
  float*         partials = (float*)(w + 1048576);        // 2 KB

  float* sel_out  = out + (size_t)S_TOK * D_OUT;
  float* loss_out = out + (size_t)S_TOK * D_OUT + (size_t)S_TOK * E_EXP;

  // weight conversion depends only on inputs — single fused launch
  k_convw_all<<<dim3(320, E_EXP), dim3(256), 0, stream>>>(W1, W2, W3, W4, Wt1, Wt2, Wt3, Wt4);

  k_router<<<dim3(S_TOK / 16), dim3(256), 0, stream>>>(x, nois, Wr, sel_out, sel_buf, te);
  k_stats<<<dim3(16), dim3(256), 0, stream>>>(sel_buf, te, partials);
  k_prefix_loss<<<dim3(1), dim3(64), 0, stream>>>(partials, counts, offsets, cursor, loss_out);
  k_listbuild<<<dim3(16), dim3(256), 0, stream>>>(te, offsets, cursor, slot_token, slot_gate, tok_slot);
  k_gather<<<dim3((2 * S_TOK * 64) / 256), dim3(256), 0, stream>>>(x, slot_token, actB);

  // Layer 1: [*,512] @ [512,500] -> relu -> actA (stride 512)
  k_gemm_mid<<<dim3(24, 8, E_EXP), dim3(256), 0, stream>>>(actB, Wt1, b1, actA, offsets, counts, 512, 512, H1D);
  // Layer 2: [*,500] @ [500,500] -> relu -> actB (stride 512)
  k_gemm_mid<<<dim3(24, 8, E_EXP), dim3(256), 0, stream>>>(actA, Wt2, b2, actB, offsets, counts, 512, 512, H2D);
  // Layer 3: [*,500] @ [500,1000] -> relu -> actA (stride 1024)
  k_gemm_mid<<<dim3(24, 16, E_EXP), dim3(256), 0, stream>>>(actB, Wt3, b3, actA, offsets, counts, 512, 1024, H3D);
  // Layer 4: [*,1000] @ [1000,256] -> eo[slot] = gate*(h3@W4+b4)   (64x64 tiles)
  k_gemm_fin<<<dim3(32, 4, E_EXP), dim3(256), 0, stream>>>(actA, Wt4, b4, eo, offsets, counts, slot_gate);
  // Combine: out[s] = eo[sl1] + eo[sl2]
  k_combine<<<dim3(S_TOK * 64 / 256), dim3(256), 0, stream>>>(eo, tok_slot, out);

  (void)in_sizes; (void)n_in; (void)out_size; (void)ws_size;
}